// Round 7
// baseline (738.734 us; speedup 1.0000x reference)
//
#include <hip/hip_runtime.h>
#include <hip/hip_bf16.h>
#include <math.h>

#define TT 100
#define NN 100
#define DD 1024
#define HH 8192
#define ILR 0.01f
#define XTP 256  // XT fp32 leading stride (floats); rows 200..255 zero-padded

typedef short bf16x8 __attribute__((ext_vector_type(8)));
typedef float f32x4 __attribute__((ext_vector_type(4)));

__device__ __forceinline__ float wave_sum64(float v) {
#pragma unroll
  for (int off = 32; off; off >>= 1) v += __shfl_xor(v, off, 64);
  return v;
}

__device__ __forceinline__ unsigned short f2bf(float x) {
  __hip_bfloat16 b = __float2bfloat16(x);
  return *(unsigned short*)&b;
}
__device__ __forceinline__ float bf2f(unsigned short u) {
  __hip_bfloat16 b = *(__hip_bfloat16*)&u;
  return __bfloat162float(b);
}

// gap map for 64-col rows (stride 68): octet starts {0,8,16,24,36,44,52,60}
// mod 32 all distinct, 16B-aligned.
__device__ __forceinline__ int gmap(int c) { return c + ((c >> 5) << 2); }

// ---------------- K0: XT[m][r] = Xall[r][m] (fp32, rows>=200 zero) and
// XT2 bf16 split (h at [m*512+r], l at [m*512+256+r]).
__global__ __launch_bounds__(256) void k0_xpose(const float* __restrict__ xt,
                                                const float* __restrict__ xr,
                                                float* __restrict__ XT,
                                                unsigned short* __restrict__ XT2) {
  __shared__ float tile[32][33];
  const int tx = threadIdx.x & 31;
  const int ty = threadIdx.x >> 5;  // 0..7
  const int m0 = blockIdx.x * 32;
  const int r0 = blockIdx.y * 32;
#pragma unroll
  for (int i = 0; i < 4; i++) {
    const int r = r0 + ty + i * 8;
    if (r < 200) {
      const float* src = (r < TT) ? (xt + r * DD) : (xr + (r - TT) * DD);
      tile[ty + i * 8][tx] = src[m0 + tx];
    }
  }
  __syncthreads();
#pragma unroll
  for (int i = 0; i < 4; i++) {
    const int r = r0 + tx;  // < 256
    const int m = m0 + ty + i * 8;
    const float v = (r < 200) ? tile[tx][ty + i * 8] : 0.f;
    XT[m * XTP + r] = v;
    const unsigned short h = f2bf(v);
    XT2[m * 512 + r] = h;
    XT2[m * 512 + 256 + r] = f2bf(v - bf2f(h));
  }
}

// ---------------- K1: Hall = tanh(Xall @ W + b).
// 512 blocks x 512 threads; 8 k-groups of 1 wave (K=128 each), private gapped
// LDS staging, register prefetch-ahead of next chunk (hides HBM latency).
__global__ __launch_bounds__(512, 4) void k1_hidden6(const float* __restrict__ XT,
                                                     const float* __restrict__ W,
                                                     const float* __restrict__ bias,
                                                     float* __restrict__ Hall) {
  __shared__ float smem[8 * 1088];  // per group: As[8][68] + Bs[8][68]
  const int tid = threadIdx.x;
  const int g = tid >> 6;   // wave / k-group
  const int t = tid & 63;   // lane
  const int flat = blockIdx.x;
  const int m8 = flat & 7;
  const int r_ = (flat >> 3) & 3;
  const int chi = flat >> 5;  // 0..15
  const int row0 = r_ * 64;
  const int col0 = (chi * 8 + m8) * 64;
  const int kbase = g * 128;
  float* As = smem + g * 1088;  // [8][68] gapped
  float* Bs = As + 544;         // [8][68] gapped

  const int arow = (t & 7) * 8;
  const int bcol = (t >> 3) * 8;
  const int ra = gmap(arow);
  const int rb = gmap(bcol);
  const int sk = t >> 3;       // staging k-row 0..7
  const int c0 = (t & 7) * 4;  // staging quad col
  const int w0_ = c0;          // gmap(c0), c0<32
  const int w1_ = c0 + 36;     // gmap(c0+32)

  const float* pXT = XT + (kbase + sk) * XTP + row0 + c0;
  const float* pW = W + (kbase + sk) * HH + col0 + c0;

  float acc[8][8];
#pragma unroll
  for (int i = 0; i < 8; i++)
#pragma unroll
    for (int j = 0; j < 8; j++) acc[i][j] = 0.f;

#define K1_STAGE(Aa, Ab, Ba, Bb)              \
  *(float4*)(As + sk * 68 + w0_) = Aa;        \
  *(float4*)(As + sk * 68 + w1_) = Ab;        \
  *(float4*)(Bs + sk * 68 + w0_) = Ba;        \
  *(float4*)(Bs + sk * 68 + w1_) = Bb;

#define K1_COMPUTE8()                                                          \
  _Pragma("unroll") for (int k = 0; k < 8; k++) {                              \
    const float4 a0_ = *(const float4*)(As + k * 68 + ra);                     \
    const float4 a1_ = *(const float4*)(As + k * 68 + ra + 4);                 \
    const float4 b0_ = *(const float4*)(Bs + k * 68 + rb);                     \
    const float4 b1_ = *(const float4*)(Bs + k * 68 + rb + 4);                 \
    const float a_[8] = {a0_.x, a0_.y, a0_.z, a0_.w,                           \
                         a1_.x, a1_.y, a1_.z, a1_.w};                          \
    const float b_[8] = {b0_.x, b0_.y, b0_.z, b0_.w,                           \
                         b1_.x, b1_.y, b1_.z, b1_.w};                          \
    _Pragma("unroll") for (int i = 0; i < 8; i++)                              \
        _Pragma("unroll") for (int j = 0; j < 8; j++)                          \
            acc[i][j] = fmaf(a_[i], b_[j], acc[i][j]);                         \
  }

  // prefetch chunk 0 into set0
  float4 A0a = *(const float4*)(pXT);
  float4 A0b = *(const float4*)(pXT + 32);
  float4 B0a = *(const float4*)(pW);
  float4 B0b = *(const float4*)(pW + 32);

#pragma unroll 1
  for (int ch2 = 0; ch2 < 16; ch2 += 2) {
    // prefetch odd chunk ch2+1 into set1
    const float* qXT = pXT + (ch2 + 1) * (8 * XTP);
    const float* qW = pW + (ch2 + 1) * (8 * HH);
    float4 A1a = *(const float4*)(qXT);
    float4 A1b = *(const float4*)(qXT + 32);
    float4 B1a = *(const float4*)(qW);
    float4 B1b = *(const float4*)(qW + 32);
    // stage+compute even chunk ch2 (set0)
    K1_STAGE(A0a, A0b, B0a, B0b)
    K1_COMPUTE8()
    // prefetch chunk ch2+2 into set0
    if (ch2 + 2 < 16) {
      const float* q2XT = pXT + (ch2 + 2) * (8 * XTP);
      const float* q2W = pW + (ch2 + 2) * (8 * HH);
      A0a = *(const float4*)(q2XT);
      A0b = *(const float4*)(q2XT + 32);
      B0a = *(const float4*)(q2W);
      B0b = *(const float4*)(q2W + 32);
    }
    // stage+compute odd chunk ch2+1 (set1)
    K1_STAGE(A1a, A1b, B1a, B1b)
    K1_COMPUTE8()
  }
#undef K1_STAGE
#undef K1_COMPUTE8

  // combine 8 k-group partials in LDS (deterministic order), then tanh+store
  __syncthreads();
  float* Cs = smem;  // [64][68], aliases groups 0-3 staging (dead)
  if (g == 0) {
#pragma unroll
    for (int i = 0; i < 8; i++) {
      *(float4*)(Cs + (arow + i) * 68 + bcol) =
          make_float4(acc[i][0], acc[i][1], acc[i][2], acc[i][3]);
      *(float4*)(Cs + (arow + i) * 68 + bcol + 4) =
          make_float4(acc[i][4], acc[i][5], acc[i][6], acc[i][7]);
    }
  }
  __syncthreads();
#pragma unroll 1
  for (int gg = 1; gg < 8; gg++) {
    if (g == gg) {
#pragma unroll
      for (int i = 0; i < 8; i++) {
        float* p = Cs + (arow + i) * 68 + bcol;
        float4 v0 = *(float4*)p;
        float4 v1 = *(float4*)(p + 4);
        v0.x += acc[i][0]; v0.y += acc[i][1]; v0.z += acc[i][2]; v0.w += acc[i][3];
        v1.x += acc[i][4]; v1.y += acc[i][5]; v1.z += acc[i][6]; v1.w += acc[i][7];
        *(float4*)p = v0;
        *(float4*)(p + 4) = v1;
      }
    }
    __syncthreads();
  }
  const int row = tid >> 3;      // 0..63
  const int cs = (tid & 7) * 8;  // 0..56
  if (row0 + row < 200) {
    const float4 c0v = *(const float4*)(Cs + row * 68 + cs);
    const float4 c1v = *(const float4*)(Cs + row * 68 + cs + 4);
    const float4 e0 = *(const float4*)(bias + col0 + cs);
    const float4 e1 = *(const float4*)(bias + col0 + cs + 4);
    float4 h0, h1;
    h0.x = tanhf(c0v.x + e0.x); h0.y = tanhf(c0v.y + e0.y);
    h0.z = tanhf(c0v.z + e0.z); h0.w = tanhf(c0v.w + e0.w);
    h1.x = tanhf(c1v.x + e1.x); h1.y = tanhf(c1v.y + e1.y);
    h1.z = tanhf(c1v.z + e1.z); h1.w = tanhf(c1v.w + e1.w);
    float* dst = Hall + (row0 + row) * HH + col0 + cs;
    *(float4*)dst = h0;
    *(float4*)(dst + 4) = h1;
  }
}

// ---------------- K2: G = Ht Ht^T via 8x8 row-group tiles (1 wave per task)
// + y0 = Ht w0. Tasks: 91 pair tasks (13 groups of 8 rows) + 13 y0 tasks.
__global__ __launch_bounds__(64) void k2_gram8(const float* __restrict__ Ht,
                                               const float* __restrict__ w0,
                                               float* __restrict__ G,
                                               float* __restrict__ y0) {
  const int wid = blockIdx.x;
  const int lane = threadIdx.x;
  if (wid < 91) {
    int a = 0, rem = wid;
    while (rem >= 13 - a) { rem -= 13 - a; a++; }
    const int b = a + rem;
    const float* Ra = Ht + (a * 8) * HH;  // rows >=100 read Hr data: benign, not stored
    const float* Rb = Ht + (b * 8) * HH;
    float acc[8][8];
#pragma unroll
    for (int r = 0; r < 8; r++)
#pragma unroll
      for (int c = 0; c < 8; c++) acc[r][c] = 0.f;
#pragma unroll 1
    for (int i = 0; i < 32; i++) {
      const int k = (lane + i * 64) * 4;
      float4 x[8];
#pragma unroll
      for (int r = 0; r < 8; r++) x[r] = *(const float4*)(Ra + r * HH + k);
#pragma unroll
      for (int c = 0; c < 8; c++) {
        const float4 u = *(const float4*)(Rb + c * HH + k);
#pragma unroll
        for (int r = 0; r < 8; r++) {
          acc[r][c] = fmaf(x[r].x, u.x, acc[r][c]);
          acc[r][c] = fmaf(x[r].y, u.y, acc[r][c]);
          acc[r][c] = fmaf(x[r].z, u.z, acc[r][c]);
          acc[r][c] = fmaf(x[r].w, u.w, acc[r][c]);
        }
      }
    }
#pragma unroll
    for (int r = 0; r < 8; r++)
#pragma unroll
      for (int c = 0; c < 8; c++) acc[r][c] = wave_sum64(acc[r][c]);
    if (lane == 0) {
#pragma unroll
      for (int r = 0; r < 8; r++) {
        const int gr = a * 8 + r;
        if (gr >= 100) break;
#pragma unroll
        for (int c = 0; c < 8; c++) {
          const int gc = b * 8 + c;
          if (gc < 100) {
            G[gr * 100 + gc] = acc[r][c];
            G[gc * 100 + gr] = acc[r][c];
          }
        }
      }
    }
  } else {  // y0 task for group a
    const int a = wid - 91;
    const float* R = Ht + (a * 8) * HH;
    float acc[8] = {0.f, 0.f, 0.f, 0.f, 0.f, 0.f, 0.f, 0.f};
#pragma unroll 1
    for (int i = 0; i < 32; i++) {
      const int k = (lane + i * 64) * 4;
      const float4 wv = *(const float4*)(w0 + k);
#pragma unroll
      for (int r = 0; r < 8; r++) {
        const float4 x = *(const float4*)(R + r * HH + k);
        acc[r] += x.x * wv.x + x.y * wv.y + x.z * wv.z + x.w * wv.w;
      }
    }
#pragma unroll
    for (int r = 0; r < 8; r++) acc[r] = wave_sum64(acc[r]);
    if (lane == 0) {
#pragma unroll
      for (int r = 0; r < 8; r++)
        if (a * 8 + r < 100) y0[a * 8 + r] = acc[r];
    }
  }
}

// ---------------- K3: sequential scalar solve for err_t (1 wave)
__global__ __launch_bounds__(64) void k3_solve(const float* __restrict__ G,
                                               const float* __restrict__ y0,
                                               const float* __restrict__ ytraj,
                                               float* __restrict__ errT) {
  __shared__ float Gs[100 * 101];
  __shared__ float y0s[100];
  __shared__ float tgt[100];
  const int l = threadIdx.x;
  for (int idx = l; idx < 10000; idx += 64) {
    Gs[(idx / 100) * 101 + (idx % 100)] = G[idx];
  }
  if (l < 50) {
    y0s[l] = y0[l];       y0s[l + 50] = y0[l + 50];
    tgt[l] = ytraj[l];    tgt[l + 50] = ytraj[l + 50];
  }
  __syncthreads();
  float e_lo = 0.f, e_hi = 0.f;
  for (int t = 0; t < TT; t++) {
    float contrib = 0.f;
    if (l < t) contrib += e_lo * Gs[l * 101 + t];
    if (l + 64 < t) contrib += e_hi * Gs[(l + 64) * 101 + t];
    contrib = wave_sum64(contrib);
    const float err = tgt[t] - (y0s[t] + ILR * contrib);
    if (t < 64) {
      if (l == t) e_lo = err;
    } else {
      if (l == t - 64) e_hi = err;
    }
    if (l == 0) errT[t] = err;
  }
}

// ---------------- K4: per-column forward scan + backward suffix-product.
__global__ __launch_bounds__(64) void k4_colscan(const float* __restrict__ Ht,
                                                 const float* __restrict__ errT,
                                                 const float* __restrict__ w0,
                                                 float* __restrict__ Ct,
                                                 float* __restrict__ wf) {
  __shared__ float es[100];
  const int tid = threadIdx.x;
  for (int i = tid; i < 100; i += 64) es[i] = errT[i];
  __syncthreads();
  const int j = blockIdx.x * 64 + tid;
  float w = w0[j];
#pragma unroll 1
  for (int tc = 0; tc < TT; tc += 10) {
    float h[10];
#pragma unroll
    for (int u = 0; u < 10; u++) h[u] = Ht[(tc + u) * HH + j];
#pragma unroll
    for (int u = 0; u < 10; u++) {
      const float e = es[tc + u];
      const float d = 1.f - h[u] * h[u];
      w += ILR * e * h[u];
      Ct[(tc + u) * HH + j] = ILR * d * (e - h[u] * w);
    }
  }
  wf[j] = w;
  float prod = 1.f;
#pragma unroll 1
  for (int tc = TT - 10; tc >= 0; tc -= 10) {
    float h[10], ct[10];
#pragma unroll
    for (int u = 9; u >= 0; u--) {
      h[u] = Ht[(tc + u) * HH + j];
      ct[u] = Ct[(tc + u) * HH + j];
    }
#pragma unroll
    for (int u = 9; u >= 0; u--) {
      Ct[(tc + u) * HH + j] = ct[u] * prod;
      prod *= (1.f - ILR * h[u] * h[u]);
    }
  }
}

// ---------------- K5: e_i = Hrand[i]·w_f - y_rand[i]
__global__ __launch_bounds__(256) void k5_pred(const float* __restrict__ Hr,
                                               const float* __restrict__ wf,
                                               const float* __restrict__ yr,
                                               float* __restrict__ e_r) {
  const int i = blockIdx.x;
  const int tid = threadIdx.x;
  const float* row = Hr + i * HH;
  float p = 0.f;
#pragma unroll
  for (int c = tid * 4; c < HH; c += 1024) {
    const float4 h4 = *(const float4*)(row + c);
    const float4 w4 = *(const float4*)(wf + c);
    p += h4.x * w4.x + h4.y * w4.y + h4.z * w4.z + h4.w * w4.w;
  }
  p = wave_sum64(p);
  __shared__ float ps[4];
  if ((tid & 63) == 0) ps[tid >> 6] = p;
  __syncthreads();
  if (tid == 0) {
    const float y = ps[0] + ps[1] + ps[2] + ps[3];
    e_r[i] = y - yr[i];
  }
}

// ---------------- K6: v_j, M rows (v*Ct in place; U), gb = colsum(M), loss
__global__ __launch_bounds__(64) void k6_mbuild(const float* __restrict__ Hr,
                                                const float* __restrict__ e_r,
                                                const float* __restrict__ wf,
                                                float* __restrict__ Ct,
                                                float* __restrict__ U,
                                                float* __restrict__ gb_out,
                                                float* __restrict__ loss_out) {
  __shared__ float es[100];
  const int tid = threadIdx.x;
  for (int i = tid; i < 100; i += 64) es[i] = e_r[i];
  __syncthreads();
  if (blockIdx.x == 0) {
    float s = es[tid] * es[tid];
    if (tid < 36) {
      const float q = es[tid + 64];
      s += q * q;
    }
    s = wave_sum64(s);
    if (tid == 0) loss_out[0] = s / (float)NN;
  }
  const int j = blockIdx.x * 64 + tid;
  const float wfj = wf[j];
  float v = 0.f;
#pragma unroll 1
  for (int ic = 0; ic < NN; ic += 10) {
    float h[10];
#pragma unroll
    for (int u = 0; u < 10; u++) h[u] = Hr[(ic + u) * HH + j];
#pragma unroll
    for (int u = 0; u < 10; u++) v += es[ic + u] * h[u];
  }
  float gb = 0.f;
#pragma unroll 1
  for (int tc = 0; tc < TT; tc += 10) {
    float ct[10];
#pragma unroll
    for (int u = 0; u < 10; u++) ct[u] = Ct[(tc + u) * HH + j];
#pragma unroll
    for (int u = 0; u < 10; u++) {
      const float m = v * ct[u];
      Ct[(tc + u) * HH + j] = m;
      gb += m;
    }
  }
#pragma unroll 1
  for (int ic = 0; ic < NN; ic += 10) {
    float h[10];
#pragma unroll
    for (int u = 0; u < 10; u++) h[u] = Hr[(ic + u) * HH + j];
#pragma unroll
    for (int u = 0; u < 10; u++) {
      const float m = es[ic + u] * wfj * (1.f - h[u] * h[u]);
      U[(ic + u) * HH + j] = m;
      gb += m;
    }
  }
  gb_out[j] = gb;
}

// ---------------- K6b: MT2[j][i] = split-bf16 of M[i][j]; i padded to 256.
// M = Ct base (rows 0..99 Ct, 100..199 U, contiguous).
__global__ __launch_bounds__(256) void k6b_mxpose(const float* __restrict__ M,
                                                  unsigned short* __restrict__ MT2) {
  __shared__ float tile[32][33];
  const int tx = threadIdx.x & 31;
  const int ty = threadIdx.x >> 5;  // 0..7
  const int j0 = blockIdx.x * 32;
  const int i0 = blockIdx.y * 32;
#pragma unroll
  for (int u = 0; u < 4; u++) {
    const int i = i0 + ty + u * 8;
    tile[ty + u * 8][tx] = (i < 200) ? M[(size_t)i * HH + j0 + tx] : 0.f;
  }
  __syncthreads();
#pragma unroll
  for (int u = 0; u < 4; u++) {
    const int j = j0 + ty + u * 8;
    const float v = tile[tx][ty + u * 8];  // = M[i0+tx][j]
    const unsigned short h = f2bf(v);
    MT2[(size_t)j * 512 + (i0 + tx)] = h;
    MT2[(size_t)j * 512 + 256 + (i0 + tx)] = f2bf(v - bf2f(h));
  }
}

// ---------------- K7: gW = Xall^T · M via bf16 MFMA, split-precision
// (AhBh + AhBl + AlBh -> fp32-faithful). A = XT2 [1024][512]b, B = MT2
// [8192][512]b, K=256 (zero-padded). Block 256 thr = 4 waves (2x2 of 64x64).
__global__ __launch_bounds__(256) void k7_mfma(const unsigned short* __restrict__ XT2,
                                               const unsigned short* __restrict__ MT2,
                                               float* __restrict__ gW) {
  const int tid = threadIdx.x;
  const int l = tid & 63;
  const int wid = tid >> 6;
  const int m0 = blockIdx.x * 128 + (wid >> 1) * 64;
  const int n0 = blockIdx.y * 128 + (wid & 1) * 64;
  const int l15 = l & 15;
  const int koff = (l >> 4) * 8;

  f32x4 acc[4][4];
#pragma unroll
  for (int i = 0; i < 4; i++)
#pragma unroll
    for (int j = 0; j < 4; j++) {
      f32x4 z = {0.f, 0.f, 0.f, 0.f};
      acc[i][j] = z;
    }

  const unsigned short* pa = XT2 + (size_t)(m0 + l15) * 512 + koff;
  const unsigned short* pb = MT2 + (size_t)(n0 + l15) * 512 + koff;

#pragma unroll 2
  for (int k0 = 0; k0 < 256; k0 += 32) {
    bf16x8 ah[4], al[4], bh[4], bl[4];
#pragma unroll
    for (int i = 0; i < 4; i++) {
      ah[i] = *(const bf16x8*)(pa + (size_t)i * 16 * 512 + k0);
      al[i] = *(const bf16x8*)(pa + (size_t)i * 16 * 512 + 256 + k0);
      bh[i] = *(const bf16x8*)(pb + (size_t)i * 16 * 512 + k0);
      bl[i] = *(const bf16x8*)(pb + (size_t)i * 16 * 512 + 256 + k0);
    }
#pragma unroll
    for (int i = 0; i < 4; i++)
#pragma unroll
      for (int j = 0; j < 4; j++) {
        acc[i][j] = __builtin_amdgcn_mfma_f32_16x16x32_bf16(ah[i], bh[j], acc[i][j], 0, 0, 0);
        acc[i][j] = __builtin_amdgcn_mfma_f32_16x16x32_bf16(ah[i], bl[j], acc[i][j], 0, 0, 0);
        acc[i][j] = __builtin_amdgcn_mfma_f32_16x16x32_bf16(al[i], bh[j], acc[i][j], 0, 0, 0);
      }
  }
  // D layout (m89-verified): col = lane&15, row = (lane>>4)*4 + reg
  const int drow = (l >> 4) * 4;
#pragma unroll
  for (int i = 0; i < 4; i++)
#pragma unroll
    for (int j = 0; j < 4; j++) {
      float* dst = gW + (size_t)(m0 + i * 16 + drow) * HH + n0 + j * 16 + l15;
#pragma unroll
      for (int r = 0; r < 4; r++) dst[(size_t)r * HH] = acc[i][j][r];
    }
}

extern "C" void kernel_launch(void* const* d_in, const int* in_sizes, int n_in,
                              void* d_out, int out_size, void* d_ws, size_t ws_size,
                              hipStream_t stream) {
  (void)in_sizes; (void)n_in; (void)out_size; (void)ws_size;
  const float* xt = (const float*)d_in[0];   // [100,1024]
  const float* yt = (const float*)d_in[1];   // [100]
  const float* xr = (const float*)d_in[2];   // [100,1024]
  const float* yr = (const float*)d_in[3];   // [100]
  const float* W = (const float*)d_in[4];    // [1024,8192]
  const float* bias = (const float*)d_in[5]; // [8192]
  const float* w0 = (const float*)d_in[6];   // [8192]
  float* out = (float*)d_out;  // [0]=loss, [1..1+D*H)=gW, then gb[H]
  float* ws = (float*)d_ws;

  float* Hall = ws;              // 200*8192
  float* Ht = Hall;
  float* Hr = Hall + TT * HH;
  float* Ct = Hall + 200 * HH;   // 100*8192 -> M rows 0..99
  float* U = Ct + TT * HH;       // 100*8192 -> M rows 100..199
  float* XT = U;                 // alias: XT fp32 (1024x256) dead before k6 writes U
  float* G = U + NN * HH;        // 100*100
  float* y0v = G + TT * TT;      // 100
  float* errT = y0v + TT;        // 100
  float* e_r = errT + TT;        // 100
  float* wf = e_r + NN;          // 8192
  unsigned short* XT2 = (unsigned short*)(wf + HH);          // 1024*512 bf16
  unsigned short* MT2 = XT2 + (size_t)1024 * 512;            // 8192*512 bf16

  k0_xpose<<<dim3(32, 8), 256, 0, stream>>>(xt, xr, XT, XT2);
  k1_hidden6<<<512, 512, 0, stream>>>(XT, W, bias, Hall);
  k2_gram8<<<104, 64, 0, stream>>>(Ht, w0, G, y0v);
  k3_solve<<<1, 64, 0, stream>>>(G, y0v, yt, errT);
  k4_colscan<<<HH / 64, 64, 0, stream>>>(Ht, errT, w0, Ct, wf);
  k5_pred<<<NN, 256, 0, stream>>>(Hr, wf, yr, e_r);
  k6_mbuild<<<HH / 64, 64, 0, stream>>>(Hr, e_r, wf, Ct, U, out + 1 + (size_t)DD * HH, out);
  k6b_mxpose<<<dim3(256, 8), 256, 0, stream>>>(Ct, MT2);
  k7_mfma<<<dim3(8, 64), 256, 0, stream>>>(XT2, MT2, out + 1);
}

// Round 8
// 232.991 us; speedup vs baseline: 3.1707x; 3.1707x over previous
//
#include <hip/hip_runtime.h>
#include <hip/hip_bf16.h>
#include <math.h>

#define TT 100
#define NN 100
#define DD 1024
#define HH 8192
#define ILR 0.01f

typedef short bf16x8 __attribute__((ext_vector_type(8)));
typedef float f32x4 __attribute__((ext_vector_type(4)));

__device__ __forceinline__ float wave_sum64(float v) {
#pragma unroll
  for (int off = 32; off; off >>= 1) v += __shfl_xor(v, off, 64);
  return v;
}

__device__ __forceinline__ unsigned short f2bf(float x) {
  __hip_bfloat16 b = __float2bfloat16(x);
  return *(unsigned short*)&b;
}
__device__ __forceinline__ float bf2f(unsigned short u) {
  __hip_bfloat16 b = *(__hip_bfloat16*)&u;
  return __bfloat162float(b);
}

// ---------------- K0: XT2[m][r] = split-bf16 of Xall[r][m] (for k7, r padded
// to 256) and XA2[r][k] = split-bf16 of Xall[r][k] row-major (for k1).
__global__ __launch_bounds__(256) void k0_xpose(const float* __restrict__ xt,
                                                const float* __restrict__ xr,
                                                unsigned short* __restrict__ XT2,
                                                unsigned short* __restrict__ XA2) {
  __shared__ float tile[32][33];
  const int tx = threadIdx.x & 31;
  const int ty = threadIdx.x >> 5;  // 0..7
  const int m0 = blockIdx.x * 32;
  const int r0 = blockIdx.y * 32;
#pragma unroll
  for (int i = 0; i < 4; i++) {
    const int r = r0 + ty + i * 8;
    float v = 0.f;
    if (r < 200) {
      const float* src = (r < TT) ? (xt + r * DD) : (xr + (r - TT) * DD);
      v = src[m0 + tx];
    }
    tile[ty + i * 8][tx] = v;
    // row-major split write (XA2): rows >=200 get zeros
    const unsigned short h = f2bf(v);
    XA2[(size_t)r * 2048 + m0 + tx] = h;
    XA2[(size_t)r * 2048 + 1024 + m0 + tx] = f2bf(v - bf2f(h));
  }
  __syncthreads();
#pragma unroll
  for (int i = 0; i < 4; i++) {
    const int r = r0 + tx;  // < 256
    const int m = m0 + ty + i * 8;
    const float v = tile[tx][ty + i * 8];  // zero for r>=200 (tile zeroed above)
    const unsigned short h = f2bf(v);
    XT2[(size_t)m * 512 + r] = h;
    XT2[(size_t)m * 512 + 256 + r] = f2bf(v - bf2f(h));
  }
}

// ---------------- K1: Hall = tanh(X @ W + b) via split-bf16 MFMA.
// 256 blocks x 256 thr (4 waves). Block owns 32 cols; wave w owns rows
// [w*64, w*64+64). Per 128-k chunk: all threads cooperatively stage the
// W[k-chunk][32 cols] tile into LDS as split-bf16 (fused transpose -> k-major),
// then each wave runs 16x16x32 MFMAs (3 passes: hh, hl, lh).
__global__ __launch_bounds__(256) void k1_mfma(const unsigned short* __restrict__ XA2,
                                               const float* __restrict__ W,
                                               const float* __restrict__ bias,
                                               float* __restrict__ Hall) {
  __shared__ unsigned short Bs[2 * 32 * 136];  // [plane][c*136 + k], pad 8/row
  const int tid = threadIdx.x;
  const int wave = tid >> 6;
  const int lane = tid & 63;
  const int l15 = lane & 15;
  const int koct = lane >> 4;  // 0..3
  const int col0 = blockIdx.x * 32;
  const int sc = tid & 31;     // staging col
  const int skp = tid >> 5;    // staging k-pair base 0..7

  f32x4 acc[4][2];
#pragma unroll
  for (int i = 0; i < 4; i++)
#pragma unroll
    for (int j = 0; j < 2; j++) {
      f32x4 z = {0.f, 0.f, 0.f, 0.f};
      acc[i][j] = z;
    }

#pragma unroll 1
  for (int ch = 0; ch < 8; ch++) {
    const int k0c = ch * 128;
    __syncthreads();  // previous chunk's reads done before overwrite
    // stage W[k0c..k0c+128][col0..col0+32] -> split bf16, k-major per col
#pragma unroll
    for (int p = 0; p < 8; p++) {
      const int k = skp * 2 + p * 16;  // even, 0..126
      const float w0v = W[(size_t)(k0c + k) * HH + col0 + sc];
      const float w1v = W[(size_t)(k0c + k + 1) * HH + col0 + sc];
      const unsigned short h0 = f2bf(w0v), h1 = f2bf(w1v);
      const unsigned short g0 = f2bf(w0v - bf2f(h0));
      const unsigned short g1 = f2bf(w1v - bf2f(h1));
      *(unsigned int*)&Bs[sc * 136 + k] = (unsigned int)h0 | ((unsigned int)h1 << 16);
      *(unsigned int*)&Bs[4352 + sc * 136 + k] = (unsigned int)g0 | ((unsigned int)g1 << 16);
    }
    __syncthreads();
#pragma unroll
    for (int ks = 0; ks < 4; ks++) {
      const int kl = ks * 32 + koct * 8;
      bf16x8 ah[4], al[4];
#pragma unroll
      for (int mf = 0; mf < 4; mf++) {
        const int row = wave * 64 + mf * 16 + l15;
        ah[mf] = *(const bf16x8*)&XA2[(size_t)row * 2048 + k0c + kl];
        al[mf] = *(const bf16x8*)&XA2[(size_t)row * 2048 + 1024 + k0c + kl];
      }
      bf16x8 bh[2], bl[2];
#pragma unroll
      for (int nf = 0; nf < 2; nf++) {
        const int c = nf * 16 + l15;
        bh[nf] = *(const bf16x8*)&Bs[c * 136 + kl];
        bl[nf] = *(const bf16x8*)&Bs[4352 + c * 136 + kl];
      }
#pragma unroll
      for (int mf = 0; mf < 4; mf++)
#pragma unroll
        for (int nf = 0; nf < 2; nf++) {
          acc[mf][nf] = __builtin_amdgcn_mfma_f32_16x16x32_bf16(ah[mf], bh[nf], acc[mf][nf], 0, 0, 0);
          acc[mf][nf] = __builtin_amdgcn_mfma_f32_16x16x32_bf16(ah[mf], bl[nf], acc[mf][nf], 0, 0, 0);
          acc[mf][nf] = __builtin_amdgcn_mfma_f32_16x16x32_bf16(al[mf], bh[nf], acc[mf][nf], 0, 0, 0);
        }
    }
  }
  // epilogue: bias + tanh + store (D layout: col=lane&15, row=(lane>>4)*4+r)
  const int drow = (lane >> 4) * 4;
#pragma unroll
  for (int mf = 0; mf < 4; mf++) {
    const int gr = wave * 64 + mf * 16 + drow;
#pragma unroll
    for (int nf = 0; nf < 2; nf++) {
      const int gc = col0 + nf * 16 + l15;
      const float bv = bias[gc];
#pragma unroll
      for (int r = 0; r < 4; r++) {
        const int row = gr + r;
        if (row < 200) Hall[(size_t)row * HH + gc] = tanhf(acc[mf][nf][r] + bv);
      }
    }
  }
}

// ---------------- K2: G = Ht Ht^T via 8x8 row-group tiles (1 wave per task)
// + y0 = Ht w0.
__global__ __launch_bounds__(64) void k2_gram8(const float* __restrict__ Ht,
                                               const float* __restrict__ w0,
                                               float* __restrict__ G,
                                               float* __restrict__ y0) {
  const int wid = blockIdx.x;
  const int lane = threadIdx.x;
  if (wid < 91) {
    int a = 0, rem = wid;
    while (rem >= 13 - a) { rem -= 13 - a; a++; }
    const int b = a + rem;
    const float* Ra = Ht + (a * 8) * HH;
    const float* Rb = Ht + (b * 8) * HH;
    float acc[8][8];
#pragma unroll
    for (int r = 0; r < 8; r++)
#pragma unroll
      for (int c = 0; c < 8; c++) acc[r][c] = 0.f;
#pragma unroll 1
    for (int i = 0; i < 32; i++) {
      const int k = (lane + i * 64) * 4;
      float4 x[8];
#pragma unroll
      for (int r = 0; r < 8; r++) x[r] = *(const float4*)(Ra + r * HH + k);
#pragma unroll
      for (int c = 0; c < 8; c++) {
        const float4 u = *(const float4*)(Rb + c * HH + k);
#pragma unroll
        for (int r = 0; r < 8; r++) {
          acc[r][c] = fmaf(x[r].x, u.x, acc[r][c]);
          acc[r][c] = fmaf(x[r].y, u.y, acc[r][c]);
          acc[r][c] = fmaf(x[r].z, u.z, acc[r][c]);
          acc[r][c] = fmaf(x[r].w, u.w, acc[r][c]);
        }
      }
    }
#pragma unroll
    for (int r = 0; r < 8; r++)
#pragma unroll
      for (int c = 0; c < 8; c++) acc[r][c] = wave_sum64(acc[r][c]);
    if (lane == 0) {
#pragma unroll
      for (int r = 0; r < 8; r++) {
        const int gr = a * 8 + r;
        if (gr >= 100) break;
#pragma unroll
        for (int c = 0; c < 8; c++) {
          const int gc = b * 8 + c;
          if (gc < 100) {
            G[gr * 100 + gc] = acc[r][c];
            G[gc * 100 + gr] = acc[r][c];
          }
        }
      }
    }
  } else {  // y0 task for group a
    const int a = wid - 91;
    const float* R = Ht + (a * 8) * HH;
    float acc[8] = {0.f, 0.f, 0.f, 0.f, 0.f, 0.f, 0.f, 0.f};
#pragma unroll 1
    for (int i = 0; i < 32; i++) {
      const int k = (lane + i * 64) * 4;
      const float4 wv = *(const float4*)(w0 + k);
#pragma unroll
      for (int r = 0; r < 8; r++) {
        const float4 x = *(const float4*)(R + r * HH + k);
        acc[r] += x.x * wv.x + x.y * wv.y + x.z * wv.z + x.w * wv.w;
      }
    }
#pragma unroll
    for (int r = 0; r < 8; r++) acc[r] = wave_sum64(acc[r]);
    if (lane == 0) {
#pragma unroll
      for (int r = 0; r < 8; r++)
        if (a * 8 + r < 100) y0[a * 8 + r] = acc[r];
    }
  }
}

// ---------------- K3: sequential scalar solve for err_t (1 wave)
__global__ __launch_bounds__(64) void k3_solve(const float* __restrict__ G,
                                               const float* __restrict__ y0,
                                               const float* __restrict__ ytraj,
                                               float* __restrict__ errT) {
  __shared__ float Gs[100 * 101];
  __shared__ float y0s[100];
  __shared__ float tgt[100];
  const int l = threadIdx.x;
  for (int idx = l; idx < 10000; idx += 64) {
    Gs[(idx / 100) * 101 + (idx % 100)] = G[idx];
  }
  if (l < 50) {
    y0s[l] = y0[l];       y0s[l + 50] = y0[l + 50];
    tgt[l] = ytraj[l];    tgt[l + 50] = ytraj[l + 50];
  }
  __syncthreads();
  float e_lo = 0.f, e_hi = 0.f;
  for (int t = 0; t < TT; t++) {
    float contrib = 0.f;
    if (l < t) contrib += e_lo * Gs[l * 101 + t];
    if (l + 64 < t) contrib += e_hi * Gs[(l + 64) * 101 + t];
    contrib = wave_sum64(contrib);
    const float err = tgt[t] - (y0s[t] + ILR * contrib);
    if (t < 64) {
      if (l == t) e_lo = err;
    } else {
      if (l == t - 64) e_hi = err;
    }
    if (l == 0) errT[t] = err;
  }
}

// ---------------- K4: per-column forward scan + backward suffix-product.
__global__ __launch_bounds__(64) void k4_colscan(const float* __restrict__ Ht,
                                                 const float* __restrict__ errT,
                                                 const float* __restrict__ w0,
                                                 float* __restrict__ Ct,
                                                 float* __restrict__ wf) {
  __shared__ float es[100];
  const int tid = threadIdx.x;
  for (int i = tid; i < 100; i += 64) es[i] = errT[i];
  __syncthreads();
  const int j = blockIdx.x * 64 + tid;
  float w = w0[j];
#pragma unroll 1
  for (int tc = 0; tc < TT; tc += 10) {
    float h[10];
#pragma unroll
    for (int u = 0; u < 10; u++) h[u] = Ht[(tc + u) * HH + j];
#pragma unroll
    for (int u = 0; u < 10; u++) {
      const float e = es[tc + u];
      const float d = 1.f - h[u] * h[u];
      w += ILR * e * h[u];
      Ct[(tc + u) * HH + j] = ILR * d * (e - h[u] * w);
    }
  }
  wf[j] = w;
  float prod = 1.f;
#pragma unroll 1
  for (int tc = TT - 10; tc >= 0; tc -= 10) {
    float h[10], ct[10];
#pragma unroll
    for (int u = 9; u >= 0; u--) {
      h[u] = Ht[(tc + u) * HH + j];
      ct[u] = Ct[(tc + u) * HH + j];
    }
#pragma unroll
    for (int u = 9; u >= 0; u--) {
      Ct[(tc + u) * HH + j] = ct[u] * prod;
      prod *= (1.f - ILR * h[u] * h[u]);
    }
  }
}

// ---------------- K5: e_i = Hrand[i]·w_f - y_rand[i]
__global__ __launch_bounds__(256) void k5_pred(const float* __restrict__ Hr,
                                               const float* __restrict__ wf,
                                               const float* __restrict__ yr,
                                               float* __restrict__ e_r) {
  const int i = blockIdx.x;
  const int tid = threadIdx.x;
  const float* row = Hr + i * HH;
  float p = 0.f;
#pragma unroll
  for (int c = tid * 4; c < HH; c += 1024) {
    const float4 h4 = *(const float4*)(row + c);
    const float4 w4 = *(const float4*)(wf + c);
    p += h4.x * w4.x + h4.y * w4.y + h4.z * w4.z + h4.w * w4.w;
  }
  p = wave_sum64(p);
  __shared__ float ps[4];
  if ((tid & 63) == 0) ps[tid >> 6] = p;
  __syncthreads();
  if (tid == 0) {
    const float y = ps[0] + ps[1] + ps[2] + ps[3];
    e_r[i] = y - yr[i];
  }
}

// ---------------- K6: v_j, M rows (v*Ct in place; U), gb = colsum(M), loss
__global__ __launch_bounds__(64) void k6_mbuild(const float* __restrict__ Hr,
                                                const float* __restrict__ e_r,
                                                const float* __restrict__ wf,
                                                float* __restrict__ Ct,
                                                float* __restrict__ U,
                                                float* __restrict__ gb_out,
                                                float* __restrict__ loss_out) {
  __shared__ float es[100];
  const int tid = threadIdx.x;
  for (int i = tid; i < 100; i += 64) es[i] = e_r[i];
  __syncthreads();
  if (blockIdx.x == 0) {
    float s = es[tid] * es[tid];
    if (tid < 36) {
      const float q = es[tid + 64];
      s += q * q;
    }
    s = wave_sum64(s);
    if (tid == 0) loss_out[0] = s / (float)NN;
  }
  const int j = blockIdx.x * 64 + tid;
  const float wfj = wf[j];
  float v = 0.f;
#pragma unroll 1
  for (int ic = 0; ic < NN; ic += 10) {
    float h[10];
#pragma unroll
    for (int u = 0; u < 10; u++) h[u] = Hr[(ic + u) * HH + j];
#pragma unroll
    for (int u = 0; u < 10; u++) v += es[ic + u] * h[u];
  }
  float gb = 0.f;
#pragma unroll 1
  for (int tc = 0; tc < TT; tc += 10) {
    float ct[10];
#pragma unroll
    for (int u = 0; u < 10; u++) ct[u] = Ct[(tc + u) * HH + j];
#pragma unroll
    for (int u = 0; u < 10; u++) {
      const float m = v * ct[u];
      Ct[(tc + u) * HH + j] = m;
      gb += m;
    }
  }
#pragma unroll 1
  for (int ic = 0; ic < NN; ic += 10) {
    float h[10];
#pragma unroll
    for (int u = 0; u < 10; u++) h[u] = Hr[(ic + u) * HH + j];
#pragma unroll
    for (int u = 0; u < 10; u++) {
      const float m = es[ic + u] * wfj * (1.f - h[u] * h[u]);
      U[(ic + u) * HH + j] = m;
      gb += m;
    }
  }
  gb_out[j] = gb;
}

// ---------------- K6b: MT2[j][i] = split-bf16 of M[i][j]; i padded to 256.
__global__ __launch_bounds__(256) void k6b_mxpose(const float* __restrict__ M,
                                                  unsigned short* __restrict__ MT2) {
  __shared__ float tile[32][33];
  const int tx = threadIdx.x & 31;
  const int ty = threadIdx.x >> 5;  // 0..7
  const int j0 = blockIdx.x * 32;
  const int i0 = blockIdx.y * 32;
#pragma unroll
  for (int u = 0; u < 4; u++) {
    const int i = i0 + ty + u * 8;
    tile[ty + u * 8][tx] = (i < 200) ? M[(size_t)i * HH + j0 + tx] : 0.f;
  }
  __syncthreads();
#pragma unroll
  for (int u = 0; u < 4; u++) {
    const int j = j0 + ty + u * 8;
    const float v = tile[tx][ty + u * 8];  // = M[i0+tx][j]
    const unsigned short h = f2bf(v);
    MT2[(size_t)j * 512 + (i0 + tx)] = h;
    MT2[(size_t)j * 512 + 256 + (i0 + tx)] = f2bf(v - bf2f(h));
  }
}

// ---------------- K7: gW = Xall^T · M via bf16 MFMA, split-precision.
__global__ __launch_bounds__(256) void k7_mfma(const unsigned short* __restrict__ XT2,
                                               const unsigned short* __restrict__ MT2,
                                               float* __restrict__ gW) {
  const int tid = threadIdx.x;
  const int l = tid & 63;
  const int wid = tid >> 6;
  const int m0 = blockIdx.x * 128 + (wid >> 1) * 64;
  const int n0 = blockIdx.y * 128 + (wid & 1) * 64;
  const int l15 = l & 15;
  const int koff = (l >> 4) * 8;

  f32x4 acc[4][4];
#pragma unroll
  for (int i = 0; i < 4; i++)
#pragma unroll
    for (int j = 0; j < 4; j++) {
      f32x4 z = {0.f, 0.f, 0.f, 0.f};
      acc[i][j] = z;
    }

  const unsigned short* pa = XT2 + (size_t)(m0 + l15) * 512 + koff;
  const unsigned short* pb = MT2 + (size_t)(n0 + l15) * 512 + koff;

#pragma unroll 2
  for (int k0 = 0; k0 < 256; k0 += 32) {
    bf16x8 ah[4], al[4], bh[4], bl[4];
#pragma unroll
    for (int i = 0; i < 4; i++) {
      ah[i] = *(const bf16x8*)(pa + (size_t)i * 16 * 512 + k0);
      al[i] = *(const bf16x8*)(pa + (size_t)i * 16 * 512 + 256 + k0);
      bh[i] = *(const bf16x8*)(pb + (size_t)i * 16 * 512 + k0);
      bl[i] = *(const bf16x8*)(pb + (size_t)i * 16 * 512 + 256 + k0);
    }
#pragma unroll
    for (int i = 0; i < 4; i++)
#pragma unroll
      for (int j = 0; j < 4; j++) {
        acc[i][j] = __builtin_amdgcn_mfma_f32_16x16x32_bf16(ah[i], bh[j], acc[i][j], 0, 0, 0);
        acc[i][j] = __builtin_amdgcn_mfma_f32_16x16x32_bf16(ah[i], bl[j], acc[i][j], 0, 0, 0);
        acc[i][j] = __builtin_amdgcn_mfma_f32_16x16x32_bf16(al[i], bh[j], acc[i][j], 0, 0, 0);
      }
  }
  const int drow = (l >> 4) * 4;
#pragma unroll
  for (int i = 0; i < 4; i++)
#pragma unroll
    for (int j = 0; j < 4; j++) {
      float* dst = gW + (size_t)(m0 + i * 16 + drow) * HH + n0 + j * 16 + l15;
#pragma unroll
      for (int r = 0; r < 4; r++) dst[(size_t)r * HH] = acc[i][j][r];
    }
}

extern "C" void kernel_launch(void* const* d_in, const int* in_sizes, int n_in,
                              void* d_out, int out_size, void* d_ws, size_t ws_size,
                              hipStream_t stream) {
  (void)in_sizes; (void)n_in; (void)out_size; (void)ws_size;
  const float* xt = (const float*)d_in[0];   // [100,1024]
  const float* yt = (const float*)d_in[1];   // [100]
  const float* xr = (const float*)d_in[2];   // [100,1024]
  const float* yr = (const float*)d_in[3];   // [100]
  const float* W = (const float*)d_in[4];    // [1024,8192]
  const float* bias = (const float*)d_in[5]; // [8192]
  const float* w0 = (const float*)d_in[6];   // [8192]
  float* out = (float*)d_out;  // [0]=loss, [1..1+D*H)=gW, then gb[H]
  float* ws = (float*)d_ws;

  float* Hall = ws;              // 200*8192
  float* Ht = Hall;
  float* Hr = Hall + TT * HH;
  float* Ct = Hall + 200 * HH;   // 100*8192 -> M rows 0..99
  float* U = Ct + TT * HH;       // 100*8192 -> M rows 100..199
  float* G = U + NN * HH;        // 100*100
  float* y0v = G + TT * TT;      // 100
  float* errT = y0v + TT;        // 100
  float* e_r = errT + TT;        // 100
  float* wf = e_r + NN;          // 8192
  unsigned short* XT2 = (unsigned short*)(wf + HH);  // 1024*512 bf16
  unsigned short* MT2 = XT2 + (size_t)1024 * 512;    // 8192*512 bf16
  unsigned short* XA2 = MT2 + (size_t)8192 * 512;    // 256*2048 bf16

  k0_xpose<<<dim3(32, 8), 256, 0, stream>>>(xt, xr, XT2, XA2);
  k1_mfma<<<256, 256, 0, stream>>>(XA2, W, bias, Hall);
  k2_gram8<<<104, 64, 0, stream>>>(Ht, w0, G, y0v);
  k3_solve<<<1, 64, 0, stream>>>(G, y0v, yt, errT);
  k4_colscan<<<HH / 64, 64, 0, stream>>>(Ht, errT, w0, Ct, wf);
  k5_pred<<<NN, 256, 0, stream>>>(Hr, wf, yr, e_r);
  k6_mbuild<<<HH / 64, 64, 0, stream>>>(Hr, e_r, wf, Ct, U, out + 1 + (size_t)DD * HH, out);
  k6b_mxpose<<<dim3(256, 8), 256, 0, stream>>>(Ct, MT2);
  k7_mfma<<<dim3(8, 64), 256, 0, stream>>>(XT2, MT2, out + 1);
}

// Round 9
// 207.920 us; speedup vs baseline: 3.5530x; 1.1206x over previous
//
#include <hip/hip_runtime.h>
#include <hip/hip_bf16.h>
#include <math.h>

#define TT 100
#define NN 100
#define DD 1024
#define HH 8192
#define ILR 0.01f

typedef short bf16x8 __attribute__((ext_vector_type(8)));
typedef float f32x4 __attribute__((ext_vector_type(4)));

// Fragment-order layout for mfma_f32_16x16x32_bf16 operands (lane conventions
// proven by r7/r8 passing): operand element (p, k) of a 16x32 fragment lives
// at lane = ((k>>3)&3)*16 + p, e = k&7. Frag block = 64 lanes x 8 bf16 = 1KB,
// so a wave load is base + lane*16B -> one coalesced 1KB transaction.
// XA2f (k1 A): plane[2] x tile[16](rows 0..255) x kb[32](K=1024): plane off 262144
// XT2f (k7 A): plane[2] x tile[64](rows 0..1023) x kb[8](K=256): plane off 262144
// MT2f (k7 B): plane[2] x tile[512](cols) x kb[8](K=256): plane off 2097152

__device__ __forceinline__ float wave_sum64(float v) {
#pragma unroll
  for (int off = 32; off; off >>= 1) v += __shfl_xor(v, off, 64);
  return v;
}

__device__ __forceinline__ unsigned short f2bf(float x) {
  __hip_bfloat16 b = __float2bfloat16(x);
  return *(unsigned short*)&b;
}
__device__ __forceinline__ float bf2f(unsigned short u) {
  __hip_bfloat16 b = *(__hip_bfloat16*)&u;
  return __bfloat162float(b);
}

// ---------------- K0: emit XA2f and XT2f (split-bf16, fragment order)
__global__ __launch_bounds__(256) void k0_frag(const float* __restrict__ xt,
                                               const float* __restrict__ xr,
                                               unsigned short* __restrict__ XA2f,
                                               unsigned short* __restrict__ XT2f) {
  const int tx = threadIdx.x & 31;   // m offset
  const int ty = threadIdx.x >> 5;   // r offset 0..7
  const int m0 = blockIdx.x * 32;
  const int r0 = blockIdx.y * 32;
#pragma unroll
  for (int i = 0; i < 4; i++) {
    const int r = r0 + ty + i * 8;   // 0..255
    const int m = m0 + tx;           // 0..1023
    float v = 0.f;
    if (r < 200) {
      const float* src = (r < TT) ? (xt + r * DD) : (xr + (r - TT) * DD);
      v = src[m];
    }
    const unsigned short h = f2bf(v);
    const unsigned short l = f2bf(v - bf2f(h));
    // XA2f: row=r, k=m
    {
      const int idx = ((((r >> 4) * 32 + (m >> 5)) * 64) +
                       ((m >> 3) & 3) * 16 + (r & 15)) * 8 + (m & 7);
      XA2f[idx] = h;
      XA2f[idx + 262144] = l;
    }
    // XT2f: row=m, k=r
    {
      const int idx = ((((m >> 4) * 8 + (r >> 5)) * 64) +
                       ((r >> 3) & 3) * 16 + (m & 15)) * 8 + (r & 7);
      XT2f[idx] = h;
      XT2f[idx + 262144] = l;
    }
  }
}

// ---------------- K1: Hall = tanh(X @ W + b), split-bf16 MFMA, frag-ordered A,
// W staged to LDS in frag order (double-buffered, 1 barrier/chunk).
// 256 blocks x 256 thr; wave w owns rows [64w, 64w+64), block owns 32 cols.
__global__ __launch_bounds__(256) void k1_mfma2(const unsigned short* __restrict__ XA2f,
                                                const float* __restrict__ W,
                                                const float* __restrict__ bias,
                                                float* __restrict__ Hall) {
  __shared__ unsigned short Bsm[2 * 8192];  // 2 bufs x (h[4096] + l[4096])
  const int tid = threadIdx.x;
  const int wave = tid >> 6;
  const int lane = tid & 63;
  const int col0 = blockIdx.x * 32;
  // staging: thread covers frag slots laneE, laneE+1 (cols colp, colp+1)
  const int nf_s = tid >> 7;               // 0..1
  const int kb_s = (tid >> 5) & 3;         // 0..3
  const int laneE = (tid * 2) & 63;        // even lane
  const int colp = col0 + nf_s * 16 + (laneE & 15);
  const int klocs = kb_s * 32 + ((laneE >> 4) << 3);
  const int sdst = ((nf_s * 4 + kb_s) * 64 + laneE) * 8;

  f32x4 acc[4][2];
#pragma unroll
  for (int i = 0; i < 4; i++)
#pragma unroll
    for (int j = 0; j < 2; j++) {
      f32x4 z = {0.f, 0.f, 0.f, 0.f};
      acc[i][j] = z;
    }

  float2 wv[8];
#define K1_LOAD(CH)                                                            \
  _Pragma("unroll") for (int e = 0; e < 8; e++) wv[e] =                        \
      *(const float2*)&W[(size_t)((CH) * 128 + klocs + e) * HH + colp];
#define K1_CVTWRITE(BUF)                                                       \
  {                                                                            \
    bf16x8 H0, H1, L0, L1;                                                     \
    _Pragma("unroll") for (int e = 0; e < 8; e++) {                            \
      const float a = wv[e].x, b = wv[e].y;                                    \
      const unsigned short ha = f2bf(a), hb = f2bf(b);                         \
      H0[e] = (short)ha; L0[e] = (short)f2bf(a - bf2f(ha));                    \
      H1[e] = (short)hb; L1[e] = (short)f2bf(b - bf2f(hb));                    \
    }                                                                          \
    unsigned short* d = Bsm + (BUF) * 8192 + sdst;                             \
    *(bf16x8*)d = H0;                                                          \
    *(bf16x8*)(d + 8) = H1;                                                    \
    *(bf16x8*)(d + 4096) = L0;                                                 \
    *(bf16x8*)(d + 4096 + 8) = L1;                                             \
  }

  K1_LOAD(0)
  K1_CVTWRITE(0)
  __syncthreads();

#pragma unroll 1
  for (int ch = 0; ch < 8; ch++) {
    if (ch < 7) { K1_LOAD(ch + 1) }
    const unsigned short* bufp = Bsm + (ch & 1) * 8192;
#pragma unroll
    for (int kb = 0; kb < 4; kb++) {
      const int kbg = ch * 4 + kb;
      bf16x8 ah[4], al[4], bh[2], bl[2];
#pragma unroll
      for (int mf = 0; mf < 4; mf++) {
        const unsigned short* pa =
            XA2f + (size_t)(((wave * 4 + mf) * 32 + kbg) * 64 + lane) * 8;
        ah[mf] = *(const bf16x8*)pa;
        al[mf] = *(const bf16x8*)(pa + 262144);
      }
#pragma unroll
      for (int nf = 0; nf < 2; nf++) {
        const unsigned short* pb = bufp + ((nf * 4 + kb) * 64 + lane) * 8;
        bh[nf] = *(const bf16x8*)pb;
        bl[nf] = *(const bf16x8*)(pb + 4096);
      }
#pragma unroll
      for (int mf = 0; mf < 4; mf++)
#pragma unroll
        for (int nf = 0; nf < 2; nf++) {
          acc[mf][nf] = __builtin_amdgcn_mfma_f32_16x16x32_bf16(ah[mf], bh[nf], acc[mf][nf], 0, 0, 0);
          acc[mf][nf] = __builtin_amdgcn_mfma_f32_16x16x32_bf16(ah[mf], bl[nf], acc[mf][nf], 0, 0, 0);
          acc[mf][nf] = __builtin_amdgcn_mfma_f32_16x16x32_bf16(al[mf], bh[nf], acc[mf][nf], 0, 0, 0);
        }
    }
    if (ch < 7) {
      K1_CVTWRITE((ch + 1) & 1)
      __syncthreads();
    }
  }
#undef K1_LOAD
#undef K1_CVTWRITE

  // epilogue: bias + tanh + store (D layout: col=lane&15, row=(lane>>4)*4+r)
  const int l15 = lane & 15;
  const int drow = (lane >> 4) * 4;
#pragma unroll
  for (int mf = 0; mf < 4; mf++) {
    const int gr = wave * 64 + mf * 16 + drow;
#pragma unroll
    for (int nf = 0; nf < 2; nf++) {
      const int gc = col0 + nf * 16 + l15;
      const float bv = bias[gc];
#pragma unroll
      for (int r = 0; r < 4; r++) {
        const int row = gr + r;
        if (row < 200) Hall[(size_t)row * HH + gc] = tanhf(acc[mf][nf][r] + bv);
      }
    }
  }
}

// ---------------- K2: G = Ht Ht^T via 8x8 row-group tiles + y0 = Ht w0
__global__ __launch_bounds__(64) void k2_gram8(const float* __restrict__ Ht,
                                               const float* __restrict__ w0,
                                               float* __restrict__ G,
                                               float* __restrict__ y0) {
  const int wid = blockIdx.x;
  const int lane = threadIdx.x;
  if (wid < 91) {
    int a = 0, rem = wid;
    while (rem >= 13 - a) { rem -= 13 - a; a++; }
    const int b = a + rem;
    const float* Ra = Ht + (a * 8) * HH;
    const float* Rb = Ht + (b * 8) * HH;
    float acc[8][8];
#pragma unroll
    for (int r = 0; r < 8; r++)
#pragma unroll
      for (int c = 0; c < 8; c++) acc[r][c] = 0.f;
#pragma unroll 1
    for (int i = 0; i < 32; i++) {
      const int k = (lane + i * 64) * 4;
      float4 x[8];
#pragma unroll
      for (int r = 0; r < 8; r++) x[r] = *(const float4*)(Ra + r * HH + k);
#pragma unroll
      for (int c = 0; c < 8; c++) {
        const float4 u = *(const float4*)(Rb + c * HH + k);
#pragma unroll
        for (int r = 0; r < 8; r++) {
          acc[r][c] = fmaf(x[r].x, u.x, acc[r][c]);
          acc[r][c] = fmaf(x[r].y, u.y, acc[r][c]);
          acc[r][c] = fmaf(x[r].z, u.z, acc[r][c]);
          acc[r][c] = fmaf(x[r].w, u.w, acc[r][c]);
        }
      }
    }
#pragma unroll
    for (int r = 0; r < 8; r++)
#pragma unroll
      for (int c = 0; c < 8; c++) acc[r][c] = wave_sum64(acc[r][c]);
    if (lane == 0) {
#pragma unroll
      for (int r = 0; r < 8; r++) {
        const int gr = a * 8 + r;
        if (gr >= 100) break;
#pragma unroll
        for (int c = 0; c < 8; c++) {
          const int gc = b * 8 + c;
          if (gc < 100) {
            G[gr * 100 + gc] = acc[r][c];
            G[gc * 100 + gr] = acc[r][c];
          }
        }
      }
    }
  } else {
    const int a = wid - 91;
    const float* R = Ht + (a * 8) * HH;
    float acc[8] = {0.f, 0.f, 0.f, 0.f, 0.f, 0.f, 0.f, 0.f};
#pragma unroll 1
    for (int i = 0; i < 32; i++) {
      const int k = (lane + i * 64) * 4;
      const float4 wvv = *(const float4*)(w0 + k);
#pragma unroll
      for (int r = 0; r < 8; r++) {
        const float4 x = *(const float4*)(R + r * HH + k);
        acc[r] += x.x * wvv.x + x.y * wvv.y + x.z * wvv.z + x.w * wvv.w;
      }
    }
#pragma unroll
    for (int r = 0; r < 8; r++) acc[r] = wave_sum64(acc[r]);
    if (lane == 0) {
#pragma unroll
      for (int r = 0; r < 8; r++)
        if (a * 8 + r < 100) y0[a * 8 + r] = acc[r];
    }
  }
}

// ---------------- K3: sequential scalar solve for err_t (1 wave)
__global__ __launch_bounds__(64) void k3_solve(const float* __restrict__ G,
                                               const float* __restrict__ y0,
                                               const float* __restrict__ ytraj,
                                               float* __restrict__ errT) {
  __shared__ float Gs[100 * 101];
  __shared__ float y0s[100];
  __shared__ float tgt[100];
  const int l = threadIdx.x;
  for (int idx = l; idx < 10000; idx += 64) {
    Gs[(idx / 100) * 101 + (idx % 100)] = G[idx];
  }
  if (l < 50) {
    y0s[l] = y0[l];       y0s[l + 50] = y0[l + 50];
    tgt[l] = ytraj[l];    tgt[l + 50] = ytraj[l + 50];
  }
  __syncthreads();
  float e_lo = 0.f, e_hi = 0.f;
  for (int t = 0; t < TT; t++) {
    float contrib = 0.f;
    if (l < t) contrib += e_lo * Gs[l * 101 + t];
    if (l + 64 < t) contrib += e_hi * Gs[(l + 64) * 101 + t];
    contrib = wave_sum64(contrib);
    const float err = tgt[t] - (y0s[t] + ILR * contrib);
    if (t < 64) {
      if (l == t) e_lo = err;
    } else {
      if (l == t - 64) e_hi = err;
    }
    if (l == 0) errT[t] = err;
  }
}

// ---------------- K4: per-column forward scan + backward suffix-product.
__global__ __launch_bounds__(64) void k4_colscan(const float* __restrict__ Ht,
                                                 const float* __restrict__ errT,
                                                 const float* __restrict__ w0,
                                                 float* __restrict__ Ct,
                                                 float* __restrict__ wf) {
  __shared__ float es[100];
  const int tid = threadIdx.x;
  for (int i = tid; i < 100; i += 64) es[i] = errT[i];
  __syncthreads();
  const int j = blockIdx.x * 64 + tid;
  float w = w0[j];
#pragma unroll 1
  for (int tc = 0; tc < TT; tc += 10) {
    float h[10];
#pragma unroll
    for (int u = 0; u < 10; u++) h[u] = Ht[(tc + u) * HH + j];
#pragma unroll
    for (int u = 0; u < 10; u++) {
      const float e = es[tc + u];
      const float d = 1.f - h[u] * h[u];
      w += ILR * e * h[u];
      Ct[(tc + u) * HH + j] = ILR * d * (e - h[u] * w);
    }
  }
  wf[j] = w;
  float prod = 1.f;
#pragma unroll 1
  for (int tc = TT - 10; tc >= 0; tc -= 10) {
    float h[10], ct[10];
#pragma unroll
    for (int u = 9; u >= 0; u--) {
      h[u] = Ht[(tc + u) * HH + j];
      ct[u] = Ct[(tc + u) * HH + j];
    }
#pragma unroll
    for (int u = 9; u >= 0; u--) {
      Ct[(tc + u) * HH + j] = ct[u] * prod;
      prod *= (1.f - ILR * h[u] * h[u]);
    }
  }
}

// ---------------- K5: e_i = Hrand[i]·w_f - y_rand[i]
__global__ __launch_bounds__(256) void k5_pred(const float* __restrict__ Hr,
                                               const float* __restrict__ wf,
                                               const float* __restrict__ yr,
                                               float* __restrict__ e_r) {
  const int i = blockIdx.x;
  const int tid = threadIdx.x;
  const float* row = Hr + i * HH;
  float p = 0.f;
#pragma unroll
  for (int c = tid * 4; c < HH; c += 1024) {
    const float4 h4 = *(const float4*)(row + c);
    const float4 w4 = *(const float4*)(wf + c);
    p += h4.x * w4.x + h4.y * w4.y + h4.z * w4.z + h4.w * w4.w;
  }
  p = wave_sum64(p);
  __shared__ float ps[4];
  if ((tid & 63) == 0) ps[tid >> 6] = p;
  __syncthreads();
  if (tid == 0) {
    const float y = ps[0] + ps[1] + ps[2] + ps[3];
    e_r[i] = y - yr[i];
  }
}

// ---------------- K6: v_j, M rows -> MT2f (frag order, split-bf16),
// gb = colsum(M), loss. M row index iM: 0..99 = v*Ct[t], 100..199 = U[i],
// 200..255 zero-padded.
__device__ __forceinline__ void mt2f_store(unsigned short* __restrict__ MT2f,
                                           int j, int iM, float m) {
  const int idx = ((((j >> 4) * 8 + (iM >> 5)) * 64) +
                   ((iM >> 3) & 3) * 16 + (j & 15)) * 8 + (iM & 7);
  const unsigned short h = f2bf(m);
  MT2f[idx] = h;
  MT2f[idx + 2097152] = f2bf(m - bf2f(h));
}

__global__ __launch_bounds__(64) void k6_mbuild(const float* __restrict__ Hr,
                                                const float* __restrict__ e_r,
                                                const float* __restrict__ wf,
                                                const float* __restrict__ Ct,
                                                unsigned short* __restrict__ MT2f,
                                                float* __restrict__ gb_out,
                                                float* __restrict__ loss_out) {
  __shared__ float es[100];
  const int tid = threadIdx.x;
  for (int i = tid; i < 100; i += 64) es[i] = e_r[i];
  __syncthreads();
  if (blockIdx.x == 0) {
    float s = es[tid] * es[tid];
    if (tid < 36) {
      const float q = es[tid + 64];
      s += q * q;
    }
    s = wave_sum64(s);
    if (tid == 0) loss_out[0] = s / (float)NN;
  }
  const int j = blockIdx.x * 64 + tid;
  const float wfj = wf[j];
  float v = 0.f;
#pragma unroll 1
  for (int ic = 0; ic < NN; ic += 10) {
    float h[10];
#pragma unroll
    for (int u = 0; u < 10; u++) h[u] = Hr[(ic + u) * HH + j];
#pragma unroll
    for (int u = 0; u < 10; u++) v += es[ic + u] * h[u];
  }
  float gb = 0.f;
#pragma unroll 1
  for (int tc = 0; tc < TT; tc += 10) {
    float ct[10];
#pragma unroll
    for (int u = 0; u < 10; u++) ct[u] = Ct[(tc + u) * HH + j];
#pragma unroll
    for (int u = 0; u < 10; u++) {
      const float m = v * ct[u];
      mt2f_store(MT2f, j, tc + u, m);
      gb += m;
    }
  }
#pragma unroll 1
  for (int ic = 0; ic < NN; ic += 10) {
    float h[10];
#pragma unroll
    for (int u = 0; u < 10; u++) h[u] = Hr[(ic + u) * HH + j];
#pragma unroll
    for (int u = 0; u < 10; u++) {
      const float m = es[ic + u] * wfj * (1.f - h[u] * h[u]);
      mt2f_store(MT2f, j, 100 + ic + u, m);
      gb += m;
    }
  }
  // zero-pad iM = 200..255
#pragma unroll 1
  for (int iM = 200; iM < 256; iM++) {
    const int idx = ((((j >> 4) * 8 + (iM >> 5)) * 64) +
                     ((iM >> 3) & 3) * 16 + (j & 15)) * 8 + (iM & 7);
    MT2f[idx] = 0;
    MT2f[idx + 2097152] = 0;
  }
  gb_out[j] = gb;
}

// ---------------- K7: gW = Xall^T · M, split-bf16 MFMA, frag-ordered operands.
// 512 blocks (8 m-tiles x 64 n-tiles of 128), 4 waves 2x2, wave = 64x64.
__global__ __launch_bounds__(256) void k7_mfma2(const unsigned short* __restrict__ XT2f,
                                                const unsigned short* __restrict__ MT2f,
                                                float* __restrict__ gW) {
  const int tid = threadIdx.x;
  const int l = tid & 63;
  const int wid = tid >> 6;
  const int m0 = blockIdx.x * 128 + (wid >> 1) * 64;
  const int n0 = blockIdx.y * 128 + (wid & 1) * 64;
  const int tA0 = m0 >> 4;
  const int tN0 = n0 >> 4;

  f32x4 acc[4][4];
#pragma unroll
  for (int i = 0; i < 4; i++)
#pragma unroll
    for (int j = 0; j < 4; j++) {
      f32x4 z = {0.f, 0.f, 0.f, 0.f};
      acc[i][j] = z;
    }

#pragma unroll 2
  for (int kb = 0; kb < 8; kb++) {
    bf16x8 ah[4], al[4], bh[4], bl[4];
#pragma unroll
    for (int i = 0; i < 4; i++) {
      const unsigned short* pa = XT2f + (size_t)(((tA0 + i) * 8 + kb) * 64 + l) * 8;
      ah[i] = *(const bf16x8*)pa;
      al[i] = *(const bf16x8*)(pa + 262144);
      const unsigned short* pb = MT2f + (size_t)(((tN0 + i) * 8 + kb) * 64 + l) * 8;
      bh[i] = *(const bf16x8*)pb;
      bl[i] = *(const bf16x8*)(pb + 2097152);
    }
#pragma unroll
    for (int i = 0; i < 4; i++)
#pragma unroll
      for (int j = 0; j < 4; j++) {
        acc[i][j] = __builtin_amdgcn_mfma_f32_16x16x32_bf16(ah[i], bh[j], acc[i][j], 0, 0, 0);
        acc[i][j] = __builtin_amdgcn_mfma_f32_16x16x32_bf16(ah[i], bl[j], acc[i][j], 0, 0, 0);
        acc[i][j] = __builtin_amdgcn_mfma_f32_16x16x32_bf16(al[i], bh[j], acc[i][j], 0, 0, 0);
      }
  }
  const int l15 = l & 15;
  const int drow = (l >> 4) * 4;
#pragma unroll
  for (int i = 0; i < 4; i++)
#pragma unroll
    for (int j = 0; j < 4; j++) {
      float* dst = gW + (size_t)(m0 + i * 16 + drow) * HH + n0 + j * 16 + l15;
#pragma unroll
      for (int r = 0; r < 4; r++) dst[(size_t)r * HH] = acc[i][j][r];
    }
}

extern "C" void kernel_launch(void* const* d_in, const int* in_sizes, int n_in,
                              void* d_out, int out_size, void* d_ws, size_t ws_size,
                              hipStream_t stream) {
  (void)in_sizes; (void)n_in; (void)out_size; (void)ws_size;
  const float* xt = (const float*)d_in[0];   // [100,1024]
  const float* yt = (const float*)d_in[1];   // [100]
  const float* xr = (const float*)d_in[2];   // [100,1024]
  const float* yr = (const float*)d_in[3];   // [100]
  const float* W = (const float*)d_in[4];    // [1024,8192]
  const float* bias = (const float*)d_in[5]; // [8192]
  const float* w0 = (const float*)d_in[6];   // [8192]
  float* out = (float*)d_out;  // [0]=loss, [1..1+D*H)=gW, then gb[H]
  float* ws = (float*)d_ws;

  float* Hall = ws;                   // 200*8192 f32
  float* Ht = Hall;
  float* Hr = Hall + TT * HH;
  float* Ct = Hall + 200 * HH;        // 100*8192 f32
  float* G = Ct + TT * HH;            // 100*100
  float* y0v = G + TT * TT;           // 100
  float* errT = y0v + TT;             // 100
  float* e_r = errT + TT;             // 100
  float* wf = e_r + NN;               // 8192
  unsigned short* XA2f = (unsigned short*)(wf + HH);  // 524288 shorts (1MB)
  unsigned short* XT2f = XA2f + 524288;               // 524288 shorts (1MB)
  unsigned short* MT2f = XT2f + 524288;               // 4194304 shorts (8MB)

  k0_frag<<<dim3(32, 8), 256, 0, stream>>>(xt, xr, XA2f, XT2f);
  k1_mfma2<<<256, 256, 0, stream>>>(XA2f, W, bias, Hall);
  k2_gram8<<<104, 64, 0, stream>>>(Ht, w0, G, y0v);
  k3_solve<<<1, 64, 0, stream>>>(G, y0v, yt, errT);
  k4_colscan<<<HH / 64, 64, 0, stream>>>(Ht, errT, w0, Ct, wf);
  k5_pred<<<NN, 256, 0, stream>>>(Hr, wf, yr, e_r);
  k6_mbuild<<<HH / 64, 64, 0, stream>>>(Hr, e_r, wf, Ct, MT2f,
                                        out + 1 + (size_t)DD * HH, out);
  k7_mfma2<<<dim3(8, 64), 256, 0, stream>>>(XT2f, MT2f, out + 1);
}

// Round 10
// 158.935 us; speedup vs baseline: 4.6480x; 1.3082x over previous
//
#include <hip/hip_runtime.h>
#include <hip/hip_bf16.h>
#include <math.h>

#define TT 100
#define NN 100
#define DD 1024
#define HH 8192
#define ILR 0.01f

typedef short bf16x8 __attribute__((ext_vector_type(8)));
typedef float f32x4 __attribute__((ext_vector_type(4)));

// Fragment-order layout for mfma_f32_16x16x32_bf16 operands (lane conventions
// proven by r7/r8/r9 passing): operand element (p, k) of a 16x32 fragment at
// lane = ((k>>3)&3)*16 + p, e = k&7. Frag block = 64 lanes x 8 bf16 = 1KB ->
// wave load = base + lane*16B = one coalesced 1KB transaction.

__device__ __forceinline__ float wave_sum64(float v) {
#pragma unroll
  for (int off = 32; off; off >>= 1) v += __shfl_xor(v, off, 64);
  return v;
}

__device__ __forceinline__ unsigned short f2bf(float x) {
  __hip_bfloat16 b = __float2bfloat16(x);
  return *(unsigned short*)&b;
}
__device__ __forceinline__ float bf2f(unsigned short u) {
  __hip_bfloat16 b = *(__hip_bfloat16*)&u;
  return __bfloat162float(b);
}

// ---------------- K0: emit XA2f and XT2f (split-bf16, fragment order)
__global__ __launch_bounds__(256) void k0_frag(const float* __restrict__ xt,
                                               const float* __restrict__ xr,
                                               unsigned short* __restrict__ XA2f,
                                               unsigned short* __restrict__ XT2f) {
  const int tx = threadIdx.x & 31;   // m offset
  const int ty = threadIdx.x >> 5;   // r offset 0..7
  const int m0 = blockIdx.x * 32;
  const int r0 = blockIdx.y * 32;
#pragma unroll
  for (int i = 0; i < 4; i++) {
    const int r = r0 + ty + i * 8;   // 0..255
    const int m = m0 + tx;           // 0..1023
    float v = 0.f;
    if (r < 200) {
      const float* src = (r < TT) ? (xt + r * DD) : (xr + (r - TT) * DD);
      v = src[m];
    }
    const unsigned short h = f2bf(v);
    const unsigned short l = f2bf(v - bf2f(h));
    // XA2f: row=r, k=m
    {
      const int idx = ((((r >> 4) * 32 + (m >> 5)) * 64) +
                       ((m >> 3) & 3) * 16 + (r & 15)) * 8 + (m & 7);
      XA2f[idx] = h;
      XA2f[idx + 262144] = l;
    }
    // XT2f: row=m, k=r
    {
      const int idx = ((((m >> 4) * 8 + (r >> 5)) * 64) +
                       ((r >> 3) & 3) * 16 + (m & 15)) * 8 + (r & 7);
      XT2f[idx] = h;
      XT2f[idx + 262144] = l;
    }
  }
}

// ---------------- K1: Hall = tanh(X @ W + b), split-bf16 MFMA, frag-ordered A,
// W staged to LDS in frag order (double-buffered, 1 barrier/chunk).
__global__ __launch_bounds__(256) void k1_mfma2(const unsigned short* __restrict__ XA2f,
                                                const float* __restrict__ W,
                                                const float* __restrict__ bias,
                                                float* __restrict__ Hall) {
  __shared__ unsigned short Bsm[2 * 8192];  // 2 bufs x (h[4096] + l[4096])
  const int tid = threadIdx.x;
  const int wave = tid >> 6;
  const int lane = tid & 63;
  const int col0 = blockIdx.x * 32;
  const int nf_s = tid >> 7;               // 0..1
  const int kb_s = (tid >> 5) & 3;         // 0..3
  const int laneE = (tid * 2) & 63;        // even lane
  const int colp = col0 + nf_s * 16 + (laneE & 15);
  const int klocs = kb_s * 32 + ((laneE >> 4) << 3);
  const int sdst = ((nf_s * 4 + kb_s) * 64 + laneE) * 8;

  f32x4 acc[4][2];
#pragma unroll
  for (int i = 0; i < 4; i++)
#pragma unroll
    for (int j = 0; j < 2; j++) {
      f32x4 z = {0.f, 0.f, 0.f, 0.f};
      acc[i][j] = z;
    }

  float2 wv[8];
#define K1_LOAD(CH)                                                            \
  _Pragma("unroll") for (int e = 0; e < 8; e++) wv[e] =                        \
      *(const float2*)&W[(size_t)((CH) * 128 + klocs + e) * HH + colp];
#define K1_CVTWRITE(BUF)                                                       \
  {                                                                            \
    bf16x8 H0, H1, L0, L1;                                                     \
    _Pragma("unroll") for (int e = 0; e < 8; e++) {                            \
      const float a = wv[e].x, b = wv[e].y;                                    \
      const unsigned short ha = f2bf(a), hb = f2bf(b);                         \
      H0[e] = (short)ha; L0[e] = (short)f2bf(a - bf2f(ha));                    \
      H1[e] = (short)hb; L1[e] = (short)f2bf(b - bf2f(hb));                    \
    }                                                                          \
    unsigned short* d = Bsm + (BUF) * 8192 + sdst;                             \
    *(bf16x8*)d = H0;                                                          \
    *(bf16x8*)(d + 8) = H1;                                                    \
    *(bf16x8*)(d + 4096) = L0;                                                 \
    *(bf16x8*)(d + 4096 + 8) = L1;                                             \
  }

  K1_LOAD(0)
  K1_CVTWRITE(0)
  __syncthreads();

#pragma unroll 1
  for (int ch = 0; ch < 8; ch++) {
    if (ch < 7) { K1_LOAD(ch + 1) }
    const unsigned short* bufp = Bsm + (ch & 1) * 8192;
#pragma unroll
    for (int kb = 0; kb < 4; kb++) {
      const int kbg = ch * 4 + kb;
      bf16x8 ah[4], al[4], bh[2], bl[2];
#pragma unroll
      for (int mf = 0; mf < 4; mf++) {
        const unsigned short* pa =
            XA2f + (size_t)(((wave * 4 + mf) * 32 + kbg) * 64 + lane) * 8;
        ah[mf] = *(const bf16x8*)pa;
        al[mf] = *(const bf16x8*)(pa + 262144);
      }
#pragma unroll
      for (int nf = 0; nf < 2; nf++) {
        const unsigned short* pb = bufp + ((nf * 4 + kb) * 64 + lane) * 8;
        bh[nf] = *(const bf16x8*)pb;
        bl[nf] = *(const bf16x8*)(pb + 4096);
      }
#pragma unroll
      for (int mf = 0; mf < 4; mf++)
#pragma unroll
        for (int nf = 0; nf < 2; nf++) {
          acc[mf][nf] = __builtin_amdgcn_mfma_f32_16x16x32_bf16(ah[mf], bh[nf], acc[mf][nf], 0, 0, 0);
          acc[mf][nf] = __builtin_amdgcn_mfma_f32_16x16x32_bf16(ah[mf], bl[nf], acc[mf][nf], 0, 0, 0);
          acc[mf][nf] = __builtin_amdgcn_mfma_f32_16x16x32_bf16(al[mf], bh[nf], acc[mf][nf], 0, 0, 0);
        }
    }
    if (ch < 7) {
      K1_CVTWRITE((ch + 1) & 1)
      __syncthreads();
    }
  }
#undef K1_LOAD
#undef K1_CVTWRITE

  const int l15 = lane & 15;
  const int drow = (lane >> 4) * 4;
#pragma unroll
  for (int mf = 0; mf < 4; mf++) {
    const int gr = wave * 64 + mf * 16 + drow;
#pragma unroll
    for (int nf = 0; nf < 2; nf++) {
      const int gc = col0 + nf * 16 + l15;
      const float bv = bias[gc];
#pragma unroll
      for (int r = 0; r < 4; r++) {
        const int row = gr + r;
        if (row < 200) Hall[(size_t)row * HH + gc] = tanhf(acc[mf][nf][r] + bv);
      }
    }
  }
}

// ---------------- K2a: split-K partial Gram. grid (104 tasks, 16 K-slices).
// Tasks 0..90: pair (a<=b) of 13 row-groups of 8 -> 8x8 partial sums.
// Tasks 91..103: y0 partials for group (task-91).
__global__ __launch_bounds__(64) void k2a_gram(const float* __restrict__ Ht,
                                               const float* __restrict__ w0,
                                               float* __restrict__ Gp,
                                               float* __restrict__ y0p) {
  __shared__ float red[64 * 65];
  const int task = blockIdx.x;
  const int z = blockIdx.y;
  const int lane = threadIdx.x;
  const int kb = z * 512;
  if (task < 91) {
    int a = 0, rem = task;
    while (rem >= 13 - a) { rem -= 13 - a; a++; }
    const int b = a + rem;
    const float* Ra = Ht + (size_t)(a * 8) * HH + kb;  // rows>=100 read Hr: benign
    const float* Rb = Ht + (size_t)(b * 8) * HH + kb;
    float acc[8][8];
#pragma unroll
    for (int r = 0; r < 8; r++)
#pragma unroll
      for (int c = 0; c < 8; c++) acc[r][c] = 0.f;
#pragma unroll
    for (int i = 0; i < 2; i++) {
      const int k = (lane + i * 64) * 4;
      float4 x[8];
#pragma unroll
      for (int r = 0; r < 8; r++) x[r] = *(const float4*)(Ra + (size_t)r * HH + k);
#pragma unroll
      for (int c = 0; c < 8; c++) {
        const float4 u = *(const float4*)(Rb + (size_t)c * HH + k);
#pragma unroll
        for (int r = 0; r < 8; r++) {
          acc[r][c] = fmaf(x[r].x, u.x, acc[r][c]);
          acc[r][c] = fmaf(x[r].y, u.y, acc[r][c]);
          acc[r][c] = fmaf(x[r].z, u.z, acc[r][c]);
          acc[r][c] = fmaf(x[r].w, u.w, acc[r][c]);
        }
      }
    }
    // cross-lane reduce via LDS transpose (stride 65 = conflict-free, fixed order)
#pragma unroll
    for (int r = 0; r < 8; r++)
#pragma unroll
      for (int c = 0; c < 8; c++) red[lane * 65 + r * 8 + c] = acc[r][c];
    __syncthreads();
    float s = 0.f;
#pragma unroll
    for (int i = 0; i < 64; i++) s += red[i * 65 + lane];
    Gp[(size_t)task * 1024 + z * 64 + lane] = s;
  } else {
    const int a = task - 91;
    const float* R = Ht + (size_t)(a * 8) * HH + kb;
    float acc[8] = {0.f, 0.f, 0.f, 0.f, 0.f, 0.f, 0.f, 0.f};
#pragma unroll
    for (int i = 0; i < 2; i++) {
      const int k = (lane + i * 64) * 4;
      const float4 wvv = *(const float4*)(w0 + kb + k);
#pragma unroll
      for (int r = 0; r < 8; r++) {
        const float4 x = *(const float4*)(R + (size_t)r * HH + k);
        acc[r] += x.x * wvv.x + x.y * wvv.y + x.z * wvv.z + x.w * wvv.w;
      }
    }
#pragma unroll
    for (int r = 0; r < 8; r++) acc[r] = wave_sum64(acc[r]);
    if (lane == 0) {
#pragma unroll
      for (int r = 0; r < 8; r++) y0p[a * 128 + z * 8 + r] = acc[r];
    }
  }
}

// ---------------- K2b: reduce partials -> G (with symmetric fill) and y0.
__global__ __launch_bounds__(128) void k2b_reduce(const float* __restrict__ Gp,
                                                  const float* __restrict__ y0p,
                                                  float* __restrict__ G,
                                                  float* __restrict__ y0) {
  const int blk = blockIdx.x;
  const int t = threadIdx.x;
  if (blk < 91) {
    if (t < 64) {
      float s = 0.f;
#pragma unroll
      for (int z = 0; z < 16; z++) s += Gp[(size_t)blk * 1024 + z * 64 + t];
      int a = 0, rem = blk;
      while (rem >= 13 - a) { rem -= 13 - a; a++; }
      const int b = a + rem;
      const int gr = a * 8 + (t >> 3);
      const int gc = b * 8 + (t & 7);
      if (gr < 100 && gc < 100) {
        G[gr * 100 + gc] = s;
        G[gc * 100 + gr] = s;
      }
    }
  } else {
    if (t < 104) {
      float s = 0.f;
#pragma unroll
      for (int z = 0; z < 16; z++) s += y0p[(t >> 3) * 128 + z * 8 + (t & 7)];
      if (t < 100) y0[t] = s;
    }
  }
}

// ---------------- K3: sequential scalar solve for err_t (1 wave)
__global__ __launch_bounds__(64) void k3_solve(const float* __restrict__ G,
                                               const float* __restrict__ y0,
                                               const float* __restrict__ ytraj,
                                               float* __restrict__ errT) {
  __shared__ float Gs[100 * 101];
  __shared__ float y0s[100];
  __shared__ float tgt[100];
  const int l = threadIdx.x;
  for (int idx = l; idx < 10000; idx += 64) {
    Gs[(idx / 100) * 101 + (idx % 100)] = G[idx];
  }
  if (l < 50) {
    y0s[l] = y0[l];       y0s[l + 50] = y0[l + 50];
    tgt[l] = ytraj[l];    tgt[l + 50] = ytraj[l + 50];
  }
  __syncthreads();
  float e_lo = 0.f, e_hi = 0.f;
  for (int t = 0; t < TT; t++) {
    float contrib = 0.f;
    if (l < t) contrib += e_lo * Gs[l * 101 + t];
    if (l + 64 < t) contrib += e_hi * Gs[(l + 64) * 101 + t];
    contrib = wave_sum64(contrib);
    const float err = tgt[t] - (y0s[t] + ILR * contrib);
    if (t < 64) {
      if (l == t) e_lo = err;
    } else {
      if (l == t - 64) e_hi = err;
    }
    if (l == 0) errT[t] = err;
  }
}

// ---------------- K4: per-column forward scan + backward suffix-product.
__global__ __launch_bounds__(64) void k4_colscan(const float* __restrict__ Ht,
                                                 const float* __restrict__ errT,
                                                 const float* __restrict__ w0,
                                                 float* __restrict__ Ct,
                                                 float* __restrict__ wf) {
  __shared__ float es[100];
  const int tid = threadIdx.x;
  for (int i = tid; i < 100; i += 64) es[i] = errT[i];
  __syncthreads();
  const int j = blockIdx.x * 64 + tid;
  float w = w0[j];
#pragma unroll 1
  for (int tc = 0; tc < TT; tc += 10) {
    float h[10];
#pragma unroll
    for (int u = 0; u < 10; u++) h[u] = Ht[(tc + u) * HH + j];
#pragma unroll
    for (int u = 0; u < 10; u++) {
      const float e = es[tc + u];
      const float d = 1.f - h[u] * h[u];
      w += ILR * e * h[u];
      Ct[(tc + u) * HH + j] = ILR * d * (e - h[u] * w);
    }
  }
  wf[j] = w;
  float prod = 1.f;
#pragma unroll 1
  for (int tc = TT - 10; tc >= 0; tc -= 10) {
    float h[10], ct[10];
#pragma unroll
    for (int u = 9; u >= 0; u--) {
      h[u] = Ht[(tc + u) * HH + j];
      ct[u] = Ct[(tc + u) * HH + j];
    }
#pragma unroll
    for (int u = 9; u >= 0; u--) {
      Ct[(tc + u) * HH + j] = ct[u] * prod;
      prod *= (1.f - ILR * h[u] * h[u]);
    }
  }
}

// ---------------- K5: e_i = Hrand[i]·w_f - y_rand[i]
__global__ __launch_bounds__(256) void k5_pred(const float* __restrict__ Hr,
                                               const float* __restrict__ wf,
                                               const float* __restrict__ yr,
                                               float* __restrict__ e_r) {
  const int i = blockIdx.x;
  const int tid = threadIdx.x;
  const float* row = Hr + i * HH;
  float p = 0.f;
#pragma unroll
  for (int c = tid * 4; c < HH; c += 1024) {
    const float4 h4 = *(const float4*)(row + c);
    const float4 w4 = *(const float4*)(wf + c);
    p += h4.x * w4.x + h4.y * w4.y + h4.z * w4.z + h4.w * w4.w;
  }
  p = wave_sum64(p);
  __shared__ float ps[4];
  if ((tid & 63) == 0) ps[tid >> 6] = p;
  __syncthreads();
  if (tid == 0) {
    const float y = ps[0] + ps[1] + ps[2] + ps[3];
    e_r[i] = y - yr[i];
  }
}

// ---------------- K6: v_j, M rows -> MT2f (frag order, split-bf16),
// gb = colsum(M), loss.
__device__ __forceinline__ void mt2f_store(unsigned short* __restrict__ MT2f,
                                           int j, int iM, float m) {
  const int idx = ((((j >> 4) * 8 + (iM >> 5)) * 64) +
                   ((iM >> 3) & 3) * 16 + (j & 15)) * 8 + (iM & 7);
  const unsigned short h = f2bf(m);
  MT2f[idx] = h;
  MT2f[idx + 2097152] = f2bf(m - bf2f(h));
}

__global__ __launch_bounds__(64) void k6_mbuild(const float* __restrict__ Hr,
                                                const float* __restrict__ e_r,
                                                const float* __restrict__ wf,
                                                const float* __restrict__ Ct,
                                                unsigned short* __restrict__ MT2f,
                                                float* __restrict__ gb_out,
                                                float* __restrict__ loss_out) {
  __shared__ float es[100];
  const int tid = threadIdx.x;
  for (int i = tid; i < 100; i += 64) es[i] = e_r[i];
  __syncthreads();
  if (blockIdx.x == 0) {
    float s = es[tid] * es[tid];
    if (tid < 36) {
      const float q = es[tid + 64];
      s += q * q;
    }
    s = wave_sum64(s);
    if (tid == 0) loss_out[0] = s / (float)NN;
  }
  const int j = blockIdx.x * 64 + tid;
  const float wfj = wf[j];
  float v = 0.f;
#pragma unroll 1
  for (int ic = 0; ic < NN; ic += 10) {
    float h[10];
#pragma unroll
    for (int u = 0; u < 10; u++) h[u] = Hr[(ic + u) * HH + j];
#pragma unroll
    for (int u = 0; u < 10; u++) v += es[ic + u] * h[u];
  }
  float gb = 0.f;
#pragma unroll 1
  for (int tc = 0; tc < TT; tc += 10) {
    float ct[10];
#pragma unroll
    for (int u = 0; u < 10; u++) ct[u] = Ct[(tc + u) * HH + j];
#pragma unroll
    for (int u = 0; u < 10; u++) {
      const float m = v * ct[u];
      mt2f_store(MT2f, j, tc + u, m);
      gb += m;
    }
  }
#pragma unroll 1
  for (int ic = 0; ic < NN; ic += 10) {
    float h[10];
#pragma unroll
    for (int u = 0; u < 10; u++) h[u] = Hr[(ic + u) * HH + j];
#pragma unroll
    for (int u = 0; u < 10; u++) {
      const float m = es[ic + u] * wfj * (1.f - h[u] * h[u]);
      mt2f_store(MT2f, j, 100 + ic + u, m);
      gb += m;
    }
  }
#pragma unroll 1
  for (int iM = 200; iM < 256; iM++) {
    const int idx = ((((j >> 4) * 8 + (iM >> 5)) * 64) +
                     ((iM >> 3) & 3) * 16 + (j & 15)) * 8 + (iM & 7);
    MT2f[idx] = 0;
    MT2f[idx + 2097152] = 0;
  }
  gb_out[j] = gb;
}

// ---------------- K7: gW = Xall^T · M, split-bf16 MFMA, frag-ordered operands.
__global__ __launch_bounds__(256) void k7_mfma2(const unsigned short* __restrict__ XT2f,
                                                const unsigned short* __restrict__ MT2f,
                                                float* __restrict__ gW) {
  const int tid = threadIdx.x;
  const int l = tid & 63;
  const int wid = tid >> 6;
  const int m0 = blockIdx.x * 128 + (wid >> 1) * 64;
  const int n0 = blockIdx.y * 128 + (wid & 1) * 64;
  const int tA0 = m0 >> 4;
  const int tN0 = n0 >> 4;

  f32x4 acc[4][4];
#pragma unroll
  for (int i = 0; i < 4; i++)
#pragma unroll
    for (int j = 0; j < 4; j++) {
      f32x4 z = {0.f, 0.f, 0.f, 0.f};
      acc[i][j] = z;
    }

#pragma unroll 2
  for (int kb = 0; kb < 8; kb++) {
    bf16x8 ah[4], al[4], bh[4], bl[4];
#pragma unroll
    for (int i = 0; i < 4; i++) {
      const unsigned short* pa = XT2f + (size_t)(((tA0 + i) * 8 + kb) * 64 + l) * 8;
      ah[i] = *(const bf16x8*)pa;
      al[i] = *(const bf16x8*)(pa + 262144);
      const unsigned short* pb = MT2f + (size_t)(((tN0 + i) * 8 + kb) * 64 + l) * 8;
      bh[i] = *(const bf16x8*)pb;
      bl[i] = *(const bf16x8*)(pb + 2097152);
    }
#pragma unroll
    for (int i = 0; i < 4; i++)
#pragma unroll
      for (int j = 0; j < 4; j++) {
        acc[i][j] = __builtin_amdgcn_mfma_f32_16x16x32_bf16(ah[i], bh[j], acc[i][j], 0, 0, 0);
        acc[i][j] = __builtin_amdgcn_mfma_f32_16x16x32_bf16(ah[i], bl[j], acc[i][j], 0, 0, 0);
        acc[i][j] = __builtin_amdgcn_mfma_f32_16x16x32_bf16(al[i], bh[j], acc[i][j], 0, 0, 0);
      }
  }
  const int l15 = l & 15;
  const int drow = (l >> 4) * 4;
#pragma unroll
  for (int i = 0; i < 4; i++)
#pragma unroll
    for (int j = 0; j < 4; j++) {
      float* dst = gW + (size_t)(m0 + i * 16 + drow) * HH + n0 + j * 16 + l15;
#pragma unroll
      for (int r = 0; r < 4; r++) dst[(size_t)r * HH] = acc[i][j][r];
    }
}

extern "C" void kernel_launch(void* const* d_in, const int* in_sizes, int n_in,
                              void* d_out, int out_size, void* d_ws, size_t ws_size,
                              hipStream_t stream) {
  (void)in_sizes; (void)n_in; (void)out_size; (void)ws_size;
  const float* xt = (const float*)d_in[0];   // [100,1024]
  const float* yt = (const float*)d_in[1];   // [100]
  const float* xr = (const float*)d_in[2];   // [100,1024]
  const float* yr = (const float*)d_in[3];   // [100]
  const float* W = (const float*)d_in[4];    // [1024,8192]
  const float* bias = (const float*)d_in[5]; // [8192]
  const float* w0 = (const float*)d_in[6];   // [8192]
  float* out = (float*)d_out;  // [0]=loss, [1..1+D*H)=gW, then gb[H]
  float* ws = (float*)d_ws;

  float* Hall = ws;                   // 200*8192 f32
  float* Ht = Hall;
  float* Hr = Hall + TT * HH;
  float* Ct = Hall + 200 * HH;        // 100*8192 f32
  float* G = Ct + TT * HH;            // 100*100
  float* y0v = G + TT * TT;           // 100
  float* errT = y0v + TT;             // 100
  float* e_r = errT + TT;             // 100
  float* wf = e_r + NN;               // 8192
  unsigned short* XA2f = (unsigned short*)(wf + HH);  // 524288 shorts (1MB)
  unsigned short* XT2f = XA2f + 524288;               // 524288 shorts (1MB)
  unsigned short* MT2f = XT2f + 524288;               // 4194304 shorts (8MB)
  float* Gp = (float*)(MT2f + 4194304);               // 91*1024 floats
  float* y0p = Gp + 91 * 1024;                        // 13*128 floats

  k0_frag<<<dim3(32, 8), 256, 0, stream>>>(xt, xr, XA2f, XT2f);
  k1_mfma2<<<256, 256, 0, stream>>>(XA2f, W, bias, Hall);
  k2a_gram<<<dim3(104, 16), 64, 0, stream>>>(Ht, w0, Gp, y0p);
  k2b_reduce<<<92, 128, 0, stream>>>(Gp, y0p, G, y0v);
  k3_solve<<<1, 64, 0, stream>>>(G, y0v, yt, errT);
  k4_colscan<<<HH / 64, 64, 0, stream>>>(Ht, errT, w0, Ct, wf);
  k5_pred<<<NN, 256, 0, stream>>>(Hr, wf, yr, e_r);
  k6_mbuild<<<HH / 64, 64, 0, stream>>>(Hr, e_r, wf, Ct, MT2f,
                                        out + 1 + (size_t)DD * HH, out);
  k7_mfma2<<<dim3(8, 64), 256, 0, stream>>>(XT2f, MT2f, out + 1);
}

// Round 11
// 128.283 us; speedup vs baseline: 5.7586x; 1.2389x over previous
//
#include <hip/hip_runtime.h>
#include <hip/hip_bf16.h>
#include <math.h>

#define TT 100
#define NN 100
#define DD 1024
#define HH 8192
#define ILR 0.01f

typedef short bf16x8 __attribute__((ext_vector_type(8)));
typedef float f32x4 __attribute__((ext_vector_type(4)));

// Fragment-order layout (proven r8-r10): operand element (p,k) of a 16x32
// fragment at lane=((k>>3)&3)*16+p, elem=k&7. Frag block = 64 lanes x 16B.

__device__ __forceinline__ float wave_sum64(float v) {
#pragma unroll
  for (int off = 32; off; off >>= 1) v += __shfl_xor(v, off, 64);
  return v;
}

__device__ __forceinline__ unsigned short f2bf(float x) {
  __hip_bfloat16 b = __float2bfloat16(x);
  return *(unsigned short*)&b;
}
__device__ __forceinline__ float bf2f(unsigned short u) {
  __hip_bfloat16 b = *(__hip_bfloat16*)&u;
  return __bfloat162float(b);
}

// ---------------- K0: emit XA2f and XT2f (split-bf16, fragment order)
__global__ __launch_bounds__(256) void k0_frag(const float* __restrict__ xt,
                                               const float* __restrict__ xr,
                                               unsigned short* __restrict__ XA2f,
                                               unsigned short* __restrict__ XT2f) {
  const int tx = threadIdx.x & 31;   // m offset
  const int ty = threadIdx.x >> 5;   // r offset 0..7
  const int m0 = blockIdx.x * 32;
  const int r0 = blockIdx.y * 32;
#pragma unroll
  for (int i = 0; i < 4; i++) {
    const int r = r0 + ty + i * 8;   // 0..255
    const int m = m0 + tx;           // 0..1023
    float v = 0.f;
    if (r < 200) {
      const float* src = (r < TT) ? (xt + r * DD) : (xr + (r - TT) * DD);
      v = src[m];
    }
    const unsigned short h = f2bf(v);
    const unsigned short l = f2bf(v - bf2f(h));
    {  // XA2f: row=r, k=m
      const int idx = ((((r >> 4) * 32 + (m >> 5)) * 64) +
                       ((m >> 3) & 3) * 16 + (r & 15)) * 8 + (m & 7);
      XA2f[idx] = h;
      XA2f[idx + 262144] = l;
    }
    {  // XT2f: row=m, k=r
      const int idx = ((((m >> 4) * 8 + (r >> 5)) * 64) +
                       ((r >> 3) & 3) * 16 + (m & 15)) * 8 + (r & 7);
      XT2f[idx] = h;
      XT2f[idx + 262144] = l;
    }
  }
}

// ---------------- K1: Hall = tanh(X @ W + b), split-bf16 MFMA.
// Grid 512 (XCD-swizzled: 4 row-tiles x 128 col-tiles of 64), 256 thr = 4
// waves (2 row-halves x 2 col-halves), wave = 32 rows x 32 cols (mf=2,nf=2).
// W chunk (128k x 64c) staged to LDS in frag-order split-bf16, double-buffered
// (64KB -> 2 blocks/CU = 8 waves/CU).
__global__ __launch_bounds__(256) void k1_mfma3(const unsigned short* __restrict__ XA2f,
                                                const float* __restrict__ W,
                                                const float* __restrict__ bias,
                                                float* __restrict__ Hall) {
  __shared__ unsigned short Bsm[2 * 16384];  // [buf][h 8192 | l 8192]
  const int tid = threadIdx.x;
  const int wid = tid >> 6;
  const int lane = tid & 63;
  const int flat = blockIdx.x;
  const int m8 = flat & 7;
  const int r_tile = (flat >> 3) & 3;
  const int chi = flat >> 5;             // 0..15
  const int c_tile = chi * 8 + m8;       // 0..127
  const int row0 = r_tile * 64;
  const int col0 = c_tile * 64;
  const int wr = wid >> 1;               // row half
  const int wc = wid & 1;                // col half

  // staging decode: thread covers slots (nfg=q, kb_s=wid, lane_s=lane), q=0..3
  const int col_s = lane & 15;                   // + nfg*16
  const int k_s = wid * 32 + ((lane >> 4) & 3) * 8;

  f32x4 acc[2][2];
#pragma unroll
  for (int i = 0; i < 2; i++)
#pragma unroll
    for (int j = 0; j < 2; j++) {
      f32x4 z = {0.f, 0.f, 0.f, 0.f};
      acc[i][j] = z;
    }

  float wv[4][8];
#define K1_LOADW(CH)                                                           \
  _Pragma("unroll") for (int q = 0; q < 4; q++)                                \
      _Pragma("unroll") for (int e = 0; e < 8; e++) wv[q][e] =                 \
          W[(size_t)((CH) * 128 + k_s + e) * HH + col0 + q * 16 + col_s];
#define K1_CVT(BUF)                                                            \
  _Pragma("unroll") for (int q = 0; q < 4; q++) {                              \
    bf16x8 Hv, Lv;                                                             \
    _Pragma("unroll") for (int e = 0; e < 8; e++) {                            \
      const float v = wv[q][e];                                                \
      const unsigned short hh = f2bf(v);                                       \
      Hv[e] = (short)hh;                                                       \
      Lv[e] = (short)f2bf(v - bf2f(hh));                                       \
    }                                                                          \
    unsigned short* d = Bsm + (BUF) * 16384 + ((q * 4 + wid) * 64 + lane) * 8; \
    *(bf16x8*)d = Hv;                                                          \
    *(bf16x8*)(d + 8192) = Lv;                                                 \
  }

  K1_LOADW(0)
  K1_CVT(0)
  __syncthreads();

#pragma unroll 1
  for (int ch = 0; ch < 8; ch++) {
    const unsigned short* buf = Bsm + (ch & 1) * 16384;
#pragma unroll
    for (int kb = 0; kb < 4; kb++) {
      const int kbg = ch * 4 + kb;
      bf16x8 ah[2], al[2], bh[2], bl[2];
#pragma unroll
      for (int mf = 0; mf < 2; mf++) {
        const int tA = r_tile * 4 + wr * 2 + mf;
        const unsigned short* pa = XA2f + (size_t)((tA * 32 + kbg) * 64 + lane) * 8;
        ah[mf] = *(const bf16x8*)pa;
        al[mf] = *(const bf16x8*)(pa + 262144);
      }
#pragma unroll
      for (int nf = 0; nf < 2; nf++) {
        const int nfg = wc * 2 + nf;
        const unsigned short* pb = buf + ((nfg * 4 + kb) * 64 + lane) * 8;
        bh[nf] = *(const bf16x8*)pb;
        bl[nf] = *(const bf16x8*)(pb + 8192);
      }
#pragma unroll
      for (int mf = 0; mf < 2; mf++)
#pragma unroll
        for (int nf = 0; nf < 2; nf++) {
          acc[mf][nf] = __builtin_amdgcn_mfma_f32_16x16x32_bf16(ah[mf], bh[nf], acc[mf][nf], 0, 0, 0);
          acc[mf][nf] = __builtin_amdgcn_mfma_f32_16x16x32_bf16(ah[mf], bl[nf], acc[mf][nf], 0, 0, 0);
          acc[mf][nf] = __builtin_amdgcn_mfma_f32_16x16x32_bf16(al[mf], bh[nf], acc[mf][nf], 0, 0, 0);
        }
    }
    if (ch < 7) {
      K1_LOADW(ch + 1)
      K1_CVT((ch + 1) & 1)
      __syncthreads();
    }
  }
#undef K1_LOADW
#undef K1_CVT

  // epilogue: D layout col=lane&15, row=(lane>>4)*4+r (proven r8-r10)
  const int l15 = lane & 15;
  const int drow = (lane >> 4) * 4;
#pragma unroll
  for (int mf = 0; mf < 2; mf++) {
    const int gr = row0 + wr * 32 + mf * 16 + drow;
#pragma unroll
    for (int nf = 0; nf < 2; nf++) {
      const int gc = col0 + wc * 32 + nf * 16 + l15;
      const float bv = bias[gc];
#pragma unroll
      for (int r = 0; r < 4; r++) {
        const int row = gr + r;
        if (row < 200) Hall[(size_t)row * HH + gc] = tanhf(acc[mf][nf][r] + bv);
      }
    }
  }
}

// ---------------- K2a: split-K partial Gram (104 tasks x 16 K-slices)
__global__ __launch_bounds__(64) void k2a_gram(const float* __restrict__ Ht,
                                               const float* __restrict__ w0,
                                               float* __restrict__ Gp,
                                               float* __restrict__ y0p) {
  __shared__ float red[64 * 65];
  const int task = blockIdx.x;
  const int z = blockIdx.y;
  const int lane = threadIdx.x;
  const int kb = z * 512;
  if (task < 91) {
    int a = 0, rem = task;
    while (rem >= 13 - a) { rem -= 13 - a; a++; }
    const int b = a + rem;
    const float* Ra = Ht + (size_t)(a * 8) * HH + kb;
    const float* Rb = Ht + (size_t)(b * 8) * HH + kb;
    float acc[8][8];
#pragma unroll
    for (int r = 0; r < 8; r++)
#pragma unroll
      for (int c = 0; c < 8; c++) acc[r][c] = 0.f;
#pragma unroll
    for (int i = 0; i < 2; i++) {
      const int k = (lane + i * 64) * 4;
      float4 x[8];
#pragma unroll
      for (int r = 0; r < 8; r++) x[r] = *(const float4*)(Ra + (size_t)r * HH + k);
#pragma unroll
      for (int c = 0; c < 8; c++) {
        const float4 u = *(const float4*)(Rb + (size_t)c * HH + k);
#pragma unroll
        for (int r = 0; r < 8; r++) {
          acc[r][c] = fmaf(x[r].x, u.x, acc[r][c]);
          acc[r][c] = fmaf(x[r].y, u.y, acc[r][c]);
          acc[r][c] = fmaf(x[r].z, u.z, acc[r][c]);
          acc[r][c] = fmaf(x[r].w, u.w, acc[r][c]);
        }
      }
    }
#pragma unroll
    for (int r = 0; r < 8; r++)
#pragma unroll
      for (int c = 0; c < 8; c++) red[lane * 65 + r * 8 + c] = acc[r][c];
    __syncthreads();
    float s = 0.f;
#pragma unroll
    for (int i = 0; i < 64; i++) s += red[i * 65 + lane];
    Gp[(size_t)task * 1024 + z * 64 + lane] = s;
  } else {
    const int a = task - 91;
    const float* R = Ht + (size_t)(a * 8) * HH + kb;
    float acc[8] = {0.f, 0.f, 0.f, 0.f, 0.f, 0.f, 0.f, 0.f};
#pragma unroll
    for (int i = 0; i < 2; i++) {
      const int k = (lane + i * 64) * 4;
      const float4 wvv = *(const float4*)(w0 + kb + k);
#pragma unroll
      for (int r = 0; r < 8; r++) {
        const float4 x = *(const float4*)(R + (size_t)r * HH + k);
        acc[r] += x.x * wvv.x + x.y * wvv.y + x.z * wvv.z + x.w * wvv.w;
      }
    }
#pragma unroll
    for (int r = 0; r < 8; r++) acc[r] = wave_sum64(acc[r]);
    if (lane == 0) {
#pragma unroll
      for (int r = 0; r < 8; r++) y0p[a * 128 + z * 8 + r] = acc[r];
    }
  }
}

// ---------------- K2b: reduce partials -> G (symmetric) and y0.
__global__ __launch_bounds__(128) void k2b_reduce(const float* __restrict__ Gp,
                                                  const float* __restrict__ y0p,
                                                  float* __restrict__ G,
                                                  float* __restrict__ y0) {
  const int blk = blockIdx.x;
  const int t = threadIdx.x;
  if (blk < 91) {
    if (t < 64) {
      float s = 0.f;
#pragma unroll
      for (int z = 0; z < 16; z++) s += Gp[(size_t)blk * 1024 + z * 64 + t];
      int a = 0, rem = blk;
      while (rem >= 13 - a) { rem -= 13 - a; a++; }
      const int b = a + rem;
      const int gr = a * 8 + (t >> 3);
      const int gc = b * 8 + (t & 7);
      if (gr < 100 && gc < 100) {
        G[gr * 100 + gc] = s;
        G[gc * 100 + gr] = s;
      }
    }
  } else {
    if (t < 104) {
      float s = 0.f;
#pragma unroll
      for (int z = 0; z < 16; z++) s += y0p[(t >> 3) * 128 + z * 8 + (t & 7)];
      if (t < 100) y0[t] = s;
    }
  }
}

// ---------------- K3: sequential scalar solve for err_t (1 wave)
__global__ __launch_bounds__(64) void k3_solve(const float* __restrict__ G,
                                               const float* __restrict__ y0,
                                               const float* __restrict__ ytraj,
                                               float* __restrict__ errT) {
  __shared__ float Gs[100 * 101];
  __shared__ float y0s[100];
  __shared__ float tgt[100];
  const int l = threadIdx.x;
  for (int idx = l; idx < 10000; idx += 64) {
    Gs[(idx / 100) * 101 + (idx % 100)] = G[idx];
  }
  if (l < 50) {
    y0s[l] = y0[l];       y0s[l + 50] = y0[l + 50];
    tgt[l] = ytraj[l];    tgt[l + 50] = ytraj[l + 50];
  }
  __syncthreads();
  float e_lo = 0.f, e_hi = 0.f;
  for (int t = 0; t < TT; t++) {
    float contrib = 0.f;
    if (l < t) contrib += e_lo * Gs[l * 101 + t];
    if (l + 64 < t) contrib += e_hi * Gs[(l + 64) * 101 + t];
    contrib = wave_sum64(contrib);
    const float err = tgt[t] - (y0s[t] + ILR * contrib);
    if (t < 64) {
      if (l == t) e_lo = err;
    } else {
      if (l == t - 64) e_hi = err;
    }
    if (l == 0) errT[t] = err;
  }
}

// ---------------- K4a: per-chunk partials S_c = sum(e*h), P_c = prod(1-lr h^2)
__global__ __launch_bounds__(64) void k4a_scan(const float* __restrict__ Ht,
                                               const float* __restrict__ errT,
                                               float* __restrict__ Sp,
                                               float* __restrict__ Pp) {
  __shared__ float es[20];
  const int c = blockIdx.y;
  const int t0 = c * 20;
  if (threadIdx.x < 20) es[threadIdx.x] = errT[t0 + threadIdx.x];
  __syncthreads();
  const int j = blockIdx.x * 64 + threadIdx.x;
  float h[20];
#pragma unroll
  for (int u = 0; u < 20; u++) h[u] = Ht[(size_t)(t0 + u) * HH + j];
  float S = 0.f, P = 1.f;
#pragma unroll
  for (int u = 0; u < 20; u++) S += es[u] * h[u];
#pragma unroll
  for (int u = 0; u < 20; u++) P *= (1.f - ILR * h[u] * h[u]);
  Sp[(size_t)c * HH + j] = S;
  Pp[(size_t)c * HH + j] = P;
}

// ---------------- K4b: per-chunk final scan -> Ct, wf
__global__ __launch_bounds__(64) void k4b_emit(const float* __restrict__ Ht,
                                               const float* __restrict__ errT,
                                               const float* __restrict__ w0,
                                               const float* __restrict__ Sp,
                                               const float* __restrict__ Pp,
                                               float* __restrict__ Ct,
                                               float* __restrict__ wf) {
  __shared__ float es[20];
  const int c = blockIdx.y;
  const int t0 = c * 20;
  if (threadIdx.x < 20) es[threadIdx.x] = errT[t0 + threadIdx.x];
  __syncthreads();
  const int j = blockIdx.x * 64 + threadIdx.x;
  float Sv[5], Pv[5];
#pragma unroll
  for (int q = 0; q < 5; q++) {
    Sv[q] = Sp[(size_t)q * HH + j];
    Pv[q] = Pp[(size_t)q * HH + j];
  }
  float w = w0[j];
#pragma unroll
  for (int q = 0; q < 5; q++)
    if (q < c) w += ILR * Sv[q];
  float PA = 1.f;
#pragma unroll
  for (int q = 0; q < 5; q++)
    if (q > c) PA *= Pv[q];
  float h[20];
#pragma unroll
  for (int u = 0; u < 20; u++) h[u] = Ht[(size_t)(t0 + u) * HH + j];
  float ct[20];
#pragma unroll
  for (int u = 0; u < 20; u++) {
    const float e = es[u];
    w += ILR * e * h[u];
    ct[u] = ILR * (1.f - h[u] * h[u]) * (e - h[u] * w);
  }
  float r = PA;
#pragma unroll
  for (int u = 19; u >= 0; u--) {
    Ct[(size_t)(t0 + u) * HH + j] = ct[u] * r;
    r *= (1.f - ILR * h[u] * h[u]);
  }
  if (c == 4) wf[j] = w;
}

// ---------------- K5: e_i = Hrand[i]·w_f - y_rand[i]
__global__ __launch_bounds__(256) void k5_pred(const float* __restrict__ Hr,
                                               const float* __restrict__ wf,
                                               const float* __restrict__ yr,
                                               float* __restrict__ e_r) {
  const int i = blockIdx.x;
  const int tid = threadIdx.x;
  const float* row = Hr + (size_t)i * HH;
  float p = 0.f;
#pragma unroll
  for (int c = tid * 4; c < HH; c += 1024) {
    const float4 h4 = *(const float4*)(row + c);
    const float4 w4 = *(const float4*)(wf + c);
    p += h4.x * w4.x + h4.y * w4.y + h4.z * w4.z + h4.w * w4.w;
  }
  p = wave_sum64(p);
  __shared__ float ps[4];
  if ((tid & 63) == 0) ps[tid >> 6] = p;
  __syncthreads();
  if (tid == 0) {
    const float y = ps[0] + ps[1] + ps[2] + ps[3];
    e_r[i] = y - yr[i];
  }
}

// ---------------- K6a: v partials Vp[c][j] = sum_{i in chunk} e_r[i]*Hr[i][j]
__global__ __launch_bounds__(64) void k6a_v(const float* __restrict__ Hr,
                                            const float* __restrict__ e_r,
                                            float* __restrict__ Vp) {
  __shared__ float es[20];
  const int c = blockIdx.y;
  const int i0 = c * 20;
  if (threadIdx.x < 20) es[threadIdx.x] = e_r[i0 + threadIdx.x];
  __syncthreads();
  const int j = blockIdx.x * 64 + threadIdx.x;
  float h[20];
#pragma unroll
  for (int u = 0; u < 20; u++) h[u] = Hr[(size_t)(i0 + u) * HH + j];
  float S = 0.f;
#pragma unroll
  for (int u = 0; u < 20; u++) S += es[u] * h[u];
  Vp[(size_t)c * HH + j] = S;
}

// ---------------- K6b: build MT2f rows (frag order, split bf16) + gb partials.
// Grid (32 j-blocks, 32 iM-octets), 256 thr. iM: 0..99 = v*Ct[t], 100..199 =
// e_r[i]*wf*(1-h^2), 200..255 = 0.
__global__ __launch_bounds__(256) void k6b_m(const float* __restrict__ Hr,
                                             const float* __restrict__ e_r,
                                             const float* __restrict__ wf,
                                             const float* __restrict__ Ct,
                                             const float* __restrict__ Vp,
                                             unsigned short* __restrict__ MT2f,
                                             float* __restrict__ gbp) {
  __shared__ float es[100];
  const int tid = threadIdx.x;
  for (int i = tid; i < 100; i += 256) es[i] = e_r[i];
  __syncthreads();
  const int j = blockIdx.x * 256 + tid;
  const int iMo = blockIdx.y;
  float v = 0.f;
#pragma unroll
  for (int c = 0; c < 5; c++) v += Vp[(size_t)c * HH + j];
  const float wfj = wf[j];
  float m[8];
#pragma unroll
  for (int e = 0; e < 8; e++) {
    const int iM = iMo * 8 + e;
    if (iM < 100) {
      m[e] = v * Ct[(size_t)iM * HH + j];
    } else if (iM < 200) {
      const float h = Hr[(size_t)(iM - 100) * HH + j];
      m[e] = es[iM - 100] * wfj * (1.f - h * h);
    } else {
      m[e] = 0.f;
    }
  }
  bf16x8 Hv, Lv;
  float gbs = 0.f;
#pragma unroll
  for (int e = 0; e < 8; e++) {
    const unsigned short hh = f2bf(m[e]);
    Hv[e] = (short)hh;
    Lv[e] = (short)f2bf(m[e] - bf2f(hh));
    gbs += m[e];
  }
  const int idx = (((j >> 4) * 8 + (iMo >> 2)) * 64 + (iMo & 3) * 16 + (j & 15)) * 8;
  *(bf16x8*)&MT2f[idx] = Hv;
  *(bf16x8*)&MT2f[idx + 2097152] = Lv;
  if (iMo < 25) gbp[(size_t)iMo * HH + j] = gbs;
}

// ---------------- K6c: gb = fixed-order sum of partials; loss.
__global__ __launch_bounds__(256) void k6c_gb(const float* __restrict__ gbp,
                                              const float* __restrict__ e_r,
                                              float* __restrict__ gb_out,
                                              float* __restrict__ loss_out) {
  const int tid = threadIdx.x;
  const int j = blockIdx.x * 256 + tid;
  float g = 0.f;
#pragma unroll
  for (int q = 0; q < 25; q++) g += gbp[(size_t)q * HH + j];
  gb_out[j] = g;
  if (blockIdx.x == 0 && tid < 64) {
    float s = e_r[tid] * e_r[tid];
    if (tid < 36) {
      const float q = e_r[tid + 64];
      s += q * q;
    }
    s = wave_sum64(s);
    if (tid == 0) loss_out[0] = s / (float)NN;
  }
}

// ---------------- K7: gW = Xall^T · M, split-bf16 MFMA, frag-ordered operands.
__global__ __launch_bounds__(256) void k7_mfma2(const unsigned short* __restrict__ XT2f,
                                                const unsigned short* __restrict__ MT2f,
                                                float* __restrict__ gW) {
  const int tid = threadIdx.x;
  const int l = tid & 63;
  const int wid = tid >> 6;
  const int m0 = blockIdx.x * 128 + (wid >> 1) * 64;
  const int n0 = blockIdx.y * 128 + (wid & 1) * 64;
  const int tA0 = m0 >> 4;
  const int tN0 = n0 >> 4;

  f32x4 acc[4][4];
#pragma unroll
  for (int i = 0; i < 4; i++)
#pragma unroll
    for (int j = 0; j < 4; j++) {
      f32x4 z = {0.f, 0.f, 0.f, 0.f};
      acc[i][j] = z;
    }

#pragma unroll 2
  for (int kb = 0; kb < 8; kb++) {
    bf16x8 ah[4], al[4], bh[4], bl[4];
#pragma unroll
    for (int i = 0; i < 4; i++) {
      const unsigned short* pa = XT2f + (size_t)(((tA0 + i) * 8 + kb) * 64 + l) * 8;
      ah[i] = *(const bf16x8*)pa;
      al[i] = *(const bf16x8*)(pa + 262144);
      const unsigned short* pb = MT2f + (size_t)(((tN0 + i) * 8 + kb) * 64 + l) * 8;
      bh[i] = *(const bf16x8*)pb;
      bl[i] = *(const bf16x8*)(pb + 2097152);
    }
#pragma unroll
    for (int i = 0; i < 4; i++)
#pragma unroll
      for (int j = 0; j < 4; j++) {
        acc[i][j] = __builtin_amdgcn_mfma_f32_16x16x32_bf16(ah[i], bh[j], acc[i][j], 0, 0, 0);
        acc[i][j] = __builtin_amdgcn_mfma_f32_16x16x32_bf16(ah[i], bl[j], acc[i][j], 0, 0, 0);
        acc[i][j] = __builtin_amdgcn_mfma_f32_16x16x32_bf16(al[i], bh[j], acc[i][j], 0, 0, 0);
      }
  }
  const int l15 = l & 15;
  const int drow = (l >> 4) * 4;
#pragma unroll
  for (int i = 0; i < 4; i++)
#pragma unroll
    for (int j = 0; j < 4; j++) {
      float* dst = gW + (size_t)(m0 + i * 16 + drow) * HH + n0 + j * 16 + l15;
#pragma unroll
      for (int r = 0; r < 4; r++) dst[(size_t)r * HH] = acc[i][j][r];
    }
}

extern "C" void kernel_launch(void* const* d_in, const int* in_sizes, int n_in,
                              void* d_out, int out_size, void* d_ws, size_t ws_size,
                              hipStream_t stream) {
  (void)in_sizes; (void)n_in; (void)out_size; (void)ws_size;
  const float* xt = (const float*)d_in[0];   // [100,1024]
  const float* yt = (const float*)d_in[1];   // [100]
  const float* xr = (const float*)d_in[2];   // [100,1024]
  const float* yr = (const float*)d_in[3];   // [100]
  const float* W = (const float*)d_in[4];    // [1024,8192]
  const float* bias = (const float*)d_in[5]; // [8192]
  const float* w0 = (const float*)d_in[6];   // [8192]
  float* out = (float*)d_out;  // [0]=loss, [1..1+D*H)=gW, then gb[H]
  float* ws = (float*)d_ws;

  float* Hall = ws;                   // 200*8192 f32
  float* Ht = Hall;
  float* Hr = Hall + TT * HH;
  float* Ct = Hall + 200 * HH;        // 100*8192 f32
  float* G = Ct + TT * HH;            // 100*100
  float* y0v = G + TT * TT;           // 100
  float* errT = y0v + TT;             // 100
  float* e_r = errT + TT;             // 100
  float* wf = e_r + NN;               // 8192
  unsigned short* XA2f = (unsigned short*)(wf + HH);  // 524288 shorts (1MB)
  unsigned short* XT2f = XA2f + 524288;               // 524288 shorts (1MB)
  unsigned short* MT2f = XT2f + 524288;               // 4194304 shorts (8MB)
  float* Gp = (float*)(MT2f + 4194304);               // 91*1024
  float* y0p = Gp + 91 * 1024;                        // 13*128
  float* Sp = y0p + 13 * 128;                         // 5*8192
  float* Pp = Sp + 5 * HH;                            // 5*8192
  float* Vp = Pp + 5 * HH;                            // 5*8192
  float* gbp = Vp + 5 * HH;                           // 25*8192

  k0_frag<<<dim3(32, 8), 256, 0, stream>>>(xt, xr, XA2f, XT2f);
  k1_mfma3<<<512, 256, 0, stream>>>(XA2f, W, bias, Hall);
  k2a_gram<<<dim3(104, 16), 64, 0, stream>>>(Ht, w0, Gp, y0p);
  k2b_reduce<<<92, 128, 0, stream>>>(Gp, y0p, G, y0v);
  k3_solve<<<1, 64, 0, stream>>>(G, y0v, yt, errT);
  k4a_scan<<<dim3(128, 5), 64, 0, stream>>>(Ht, errT, Sp, Pp);
  k4b_emit<<<dim3(128, 5), 64, 0, stream>>>(Ht, errT, w0, Sp, Pp, Ct, wf);
  k5_pred<<<NN, 256, 0, stream>>>(Hr, wf, yr, e_r);
  k6a_v<<<dim3(128, 5), 64, 0, stream>>>(Hr, e_r, Vp);
  k6b_m<<<dim3(32, 32), 256, 0, stream>>>(Hr, e_r, wf, Ct, Vp, MT2f, gbp);
  k6c_gb<<<32, 256, 0, stream>>>(gbp, e_r, out + 1 + (size_t)DD * HH, out);
  k7_mfma2<<<dim3(8, 64), 256, 0, stream>>>(XT2f, MT2f, out + 1);
}